// Round 1
// baseline (39994.614 us; speedup 1.0000x reference)
//
#include <hip/hip_runtime.h>

typedef __attribute__((ext_vector_type(8))) short bf16x8;
typedef __attribute__((ext_vector_type(4))) float f32x4;
typedef const __attribute__((address_space(1))) void* gas_ptr;
typedef __attribute__((address_space(3))) void* las_ptr;

__device__ __forceinline__ unsigned short f2bf(float f) {
  unsigned int u = __float_as_uint(f);
  return (unsigned short)((u + 0x7fffu + ((u >> 16) & 1u)) >> 16);  // RNE
}
__device__ __forceinline__ float bflo(unsigned int u) { return __uint_as_float(u << 16); }
__device__ __forceinline__ float bfhi(unsigned int u) { return __uint_as_float(u & 0xffff0000u); }
__device__ __forceinline__ unsigned int cvt_pk_bf16(float a, float b) {
  unsigned int r;
  asm volatile("v_cvt_pk_bf16_f32 %0, %1, %2" : "=v"(r) : "v"(a), "v"(b));
  return r;
}
__device__ __forceinline__ float sigm(float x) { return 1.0f / (1.0f + __expf(-x)); }

// ---------------- grid-wide sense-reversing barrier (all 512 blocks co-resident) ----------------
__device__ __forceinline__ void gbar(int* cnt, int* sense, int target, int nblk) {
  __syncthreads();
  if (threadIdx.x == 0) {
    __threadfence();  // agent-scope release of this block's prior stores
    if (__hip_atomic_fetch_add(cnt, 1, __ATOMIC_ACQ_REL, __HIP_MEMORY_SCOPE_AGENT) == nblk - 1) {
      __hip_atomic_store(cnt, 0, __ATOMIC_RELAXED, __HIP_MEMORY_SCOPE_AGENT);
      __hip_atomic_store(sense, target, __ATOMIC_RELEASE, __HIP_MEMORY_SCOPE_AGENT);
    } else {
      while (__hip_atomic_load(sense, __ATOMIC_ACQUIRE, __HIP_MEMORY_SCOPE_AGENT) != target) {
        __builtin_amdgcn_s_sleep(2);
      }
    }
    __threadfence();  // agent-scope acquire: invalidate stale L1/L2 before data reads
  }
  __syncthreads();
}

// ---------------- K1: copy h0/c0 into double-buffered state, zero barrier ----------------
__global__ __launch_bounds__(256) void init_kernel(
    const float* __restrict__ h0_in, const float* __restrict__ c0_in,
    float* __restrict__ h0buf, float* __restrict__ h1buf,
    float* __restrict__ c0s, float* __restrict__ c1s, int* __restrict__ bar)
{
  int j = blockIdx.x * 256 + threadIdx.x;  // 0..8191
  if (j < 2) bar[j] = 0;
#pragma unroll
  for (int q = 0; q < 4; ++q) {
    int f = (j + q * 8192) * 4;  // fp32 index, 0..131068
    if (f < 32768) {                       // layer0 h -> h0buf slot0
      *(float4*)(h0buf + f) = *(const float4*)(h0_in + f);
    } else if (f < 65536) {                // layer1 h -> h1buf slot1 (== offset 32768)
      *(float4*)(h1buf + f) = *(const float4*)(h0_in + f);
    } else if (f < 98304) {                // layer0 c
      *(float4*)(c0s + (f - 65536)) = *(const float4*)(c0_in + (f - 65536));
    } else {                               // layer1 c
      *(float4*)(c1s + (f - 98304)) = *(const float4*)(c0_in + (f - 65536));
    }
  }
}

// ---------------- K2: dec_W [1024][32000] f32 -> Wt [32000][1024] bf16 ----------------
__global__ __launch_bounds__(256) void transpose_decw_kernel(
    const float* __restrict__ decW, unsigned short* __restrict__ Wt)
{
  __shared__ float tile[64 * 68];
  const int bid = blockIdx.x;         // 8000 = 16 k-tiles x 500 n-tiles
  const int k0 = (bid & 15) * 64;
  const int n0 = (bid >> 4) * 64;
  const int tid = threadIdx.x;
  {
    const int kl = tid >> 4, c4 = (tid & 15) * 4;
#pragma unroll
    for (int i = 0; i < 4; ++i) {
      const int kr = kl + 16 * i;
      *(float4*)(tile + kr * 68 + c4) =
          *(const float4*)(decW + (size_t)(k0 + kr) * 32000 + n0 + c4);
    }
  }
  __syncthreads();
  {
    const int nl = tid >> 3, kc = (tid & 7) * 8;
#pragma unroll
    for (int h2 = 0; h2 < 2; ++h2) {
      const int n = nl + 32 * h2;
      float tv[8];
#pragma unroll
      for (int q = 0; q < 8; ++q) tv[q] = tile[(kc + q) * 68 + n];
      uint4 u;
      u.x = cvt_pk_bf16(tv[0], tv[1]);
      u.y = cvt_pk_bf16(tv[2], tv[3]);
      u.z = cvt_pk_bf16(tv[4], tv[5]);
      u.w = cvt_pk_bf16(tv[6], tv[7]);
      *(uint4*)(Wt + (size_t)(n0 + n) * 1024 + k0 + kc) = u;
    }
  }
}

// ---------------- K3: pipelined 2-layer LSTM scan, 129 phases ----------------
// 512 blocks: bid>>8 = layer, (bid&255)*4 = first hidden unit (4 units => 16 gate cols).
// Per phase: gates[32b x 16c] = x_cat[32 x 2048] @ W-slice, 16-way K-split across threads,
// x staged in LDS as bf16 [1024][32] per half-K pass, weights streamed fp32 from L2/L3.
__global__ __launch_bounds__(256, 2) void lstm_seq_kernel(
    const int* __restrict__ tokens, const float* __restrict__ etab,
    const float* __restrict__ W, const float* __restrict__ bias,
    float* __restrict__ h0buf, float* __restrict__ h1buf,
    float* __restrict__ c0s, float* __restrict__ c1s,
    unsigned short* __restrict__ hseq,
    float* __restrict__ out_tail, int* __restrict__ bar)
{
  extern __shared__ char dsm[];                      // 65536 B dynamic
  unsigned short* xl = (unsigned short*)dsm;         // [1024][32] bf16 (quad-swizzled)
  float* red = (float*)dsm;                          // [16][516] f32 (overlay, after x dead)
  float* glds = (float*)(dsm + 33152);               // [32][36] f32 gates

  const int tid = threadIdx.x;
  const int bid = blockIdx.x;
  const int layer = bid >> 8;
  const int u0 = (bid & 255) * 4;
  const float* Wl = W + (size_t)layer * 2048 * 4096 + u0;
  const float* bl = bias + layer * 4096;
  float* hbuf = layer ? h1buf : h0buf;
  float* cst = layer ? c1s : c0s;

  const int ksec = tid >> 4;      // 16-way K split
  const int pos = tid & 15;
  const int bg = pos >> 1;        // 8 batch groups of 4
  const int cg = pos & 1;         // 2 col groups of 8 (gates 2cg,2cg+1)
  const int b0q = bg * 4;
  const int nblk = (int)gridDim.x;

  for (int p = 0; p <= 128; ++p) {
    const bool active = layer ? (p >= 1) : (p < 128);
    if (active) {
      const int t = layer ? (p - 1) : p;
      // h0buf[p&1] holds h0(p-1); hbuf[p&1] holds own h(prev); write slot (p+1)&1
      const float* xlo = layer ? (h0buf + (p & 1) * 32768) : (const float*)0;
      const float* xhi = (layer ? h1buf : h0buf) + (p & 1) * 32768;

      float acc[4][8];
#pragma unroll
      for (int i = 0; i < 4; ++i)
#pragma unroll
        for (int j = 0; j < 8; ++j) acc[i][j] = 0.0f;

#pragma unroll 1
      for (int pass = 0; pass < 2; ++pass) {
        __syncthreads();
        {  // stage x half: 1024k x 32b -> bf16 LDS, coalesced f4 loads + reg transpose
          const bool use_tok = (layer == 0) && (pass == 0);
          const float* xsrc = pass ? xhi : xlo;
          const int k4 = tid * 4;
#pragma unroll 1
          for (int bq = 0; bq < 8; ++bq) {
            const float *r0, *r1, *r2, *r3;
            if (use_tok) {  // embedding gather fused: layer0 low-K input = emb_table[token]
              r0 = etab + (size_t)tokens[t * 32 + bq * 4 + 0] * 1024;
              r1 = etab + (size_t)tokens[t * 32 + bq * 4 + 1] * 1024;
              r2 = etab + (size_t)tokens[t * 32 + bq * 4 + 2] * 1024;
              r3 = etab + (size_t)tokens[t * 32 + bq * 4 + 3] * 1024;
            } else {
              r0 = xsrc + (bq * 4 + 0) * 1024;
              r1 = xsrc + (bq * 4 + 1) * 1024;
              r2 = xsrc + (bq * 4 + 2) * 1024;
              r3 = xsrc + (bq * 4 + 3) * 1024;
            }
            float4 v0 = *(const float4*)(r0 + k4);
            float4 v1 = *(const float4*)(r1 + k4);
            float4 v2 = *(const float4*)(r2 + k4);
            float4 v3 = *(const float4*)(r3 + k4);
            const float a0[4] = {v0.x, v0.y, v0.z, v0.w};
            const float a1[4] = {v1.x, v1.y, v1.z, v1.w};
            const float a2[4] = {v2.x, v2.y, v2.z, v2.w};
            const float a3[4] = {v3.x, v3.y, v3.z, v3.w};
#pragma unroll
            for (int q = 0; q < 4; ++q) {
              const int k = k4 + q;
              const int swz = (((k >> 2) ^ (k >> 5)) & 7) << 2;  // bank spread, quad-preserving
              unsigned int w0 = cvt_pk_bf16(a0[q], a1[q]);
              unsigned int w1 = cvt_pk_bf16(a2[q], a3[q]);
              *(uint2*)(xl + (size_t)k * 32 + ((bq * 4) ^ swz)) = make_uint2(w0, w1);
            }
          }
        }
        __syncthreads();
        // GEMM slice: this thread's k in [pass*1024 + ksec*64, +64)
        const float* wrow = Wl + (size_t)(pass * 1024 + ksec * 64) * 4096;
        const int kb = ksec * 64;
#pragma unroll 4
        for (int kk = 0; kk < 64; ++kk) {
          const int k = kb + kk;
          float4 wA = *(const float4*)(wrow + (size_t)kk * 4096 + 2048 * cg);
          float4 wB = *(const float4*)(wrow + (size_t)kk * 4096 + 2048 * cg + 1024);
          const int swz = (((k >> 2) ^ (k >> 5)) & 7) << 2;
          const uint2 xr = *(const uint2*)(xl + (size_t)k * 32 + (b0q ^ swz));
          const float xv[4] = {bflo(xr.x), bfhi(xr.x), bflo(xr.y), bfhi(xr.y)};
          const float wv[8] = {wA.x, wA.y, wA.z, wA.w, wB.x, wB.y, wB.z, wB.w};
#pragma unroll
          for (int i = 0; i < 4; ++i)
#pragma unroll
            for (int j = 0; j < 8; ++j)
              acc[i][j] = __builtin_fmaf(xv[i], wv[j], acc[i][j]);
        }
      }
      // cross-ksec reduction via LDS (overlays x region)
      __syncthreads();
#pragma unroll
      for (int i = 0; i < 4; ++i) {
        const int ii = i ^ (pos & 3);  // xor-swizzle rows to spread banks
        float* rp = red + ksec * 516 + pos * 32 + ii * 8;
        *(float4*)(rp) = make_float4(acc[i][0], acc[i][1], acc[i][2], acc[i][3]);
        *(float4*)(rp + 4) = make_float4(acc[i][4], acc[i][5], acc[i][6], acc[i][7]);
      }
      __syncthreads();
      {
        const int pos_o = tid >> 4;
        const int e0 = (tid & 15) * 2;
        const int i_o = e0 >> 3;
        const int j0 = e0 & 7;
        const int ii = i_o ^ (pos_o & 3);
        float s0 = 0.0f, s1 = 0.0f;
#pragma unroll
        for (int ks = 0; ks < 16; ++ks) {
          const float* rp = red + ks * 516 + pos_o * 32 + ii * 8 + j0;
          s0 += rp[0];
          s1 += rp[1];
        }
        const int c0l = (pos_o & 1) * 8 + j0;       // local col 0..15 = gate*4 + uo
        const int b = (pos_o >> 1) * 4 + i_o;
        const int g0 = c0l >> 2, uo0 = c0l & 3;
        s0 += bl[g0 * 1024 + u0 + uo0];
        s1 += bl[g0 * 1024 + u0 + uo0 + 1];
        glds[b * 36 + c0l] = s0;
        glds[b * 36 + c0l + 1] = s1;
      }
      __syncthreads();
      // elementwise cell update: 128 threads = 32b x 4 units
      if (tid < 128) {
        const int b = tid >> 2, uo = tid & 3, u = u0 + uo;
        const float gi = glds[b * 36 + 0 + uo];
        const float gj = glds[b * 36 + 4 + uo];
        const float gf = glds[b * 36 + 8 + uo];
        const float go = glds[b * 36 + 12 + uo];
        const float cold = cst[b * 1024 + u];
        const float cn = cold * sigm(gf) + sigm(gi) * tanhf(gj);
        const float hn = tanhf(cn) * sigm(go);
        cst[b * 1024 + u] = cn;
        hbuf[((p + 1) & 1) * 32768 + b * 1024 + u] = hn;
        if (layer) hseq[(size_t)t * 32768 + b * 1024 + u] = f2bf(hn);
        if (t == 127) {
          out_tail[layer * 32768 + b * 1024 + u] = hn;           // h_last
          out_tail[65536 + layer * 32768 + b * 1024 + u] = cn;   // c_last
        }
      }
    }
    if (p < 128) gbar(bar, bar + 1, (p & 1) ^ 1, nblk);
  }
}

// ---------------- K4: decoder bf16 MFMA GEMM, 128x128 tile, BK=32, double-buffered ----------------
__global__ __launch_bounds__(256) void decoder_kernel(
    const unsigned short* __restrict__ A,   // hseq  [4096][1024] bf16
    const unsigned short* __restrict__ Bt,  // Wt    [32000][1024] bf16 (dec_W^T)
    const float* __restrict__ decb,
    float* __restrict__ out)                // [4096][32000] f32
{
  __shared__ unsigned short Al[2][128 * 32];
  __shared__ unsigned short Bl[2][128 * 32];

  const int bid = blockIdx.x;
  const int swz = (bid & 7) * 1000 + (bid >> 3);  // XCD-contiguous tile chunks (8000 % 8 == 0)
  const int mt = swz / 250, nt = swz % 250;
  const int m0 = mt * 128, n0 = nt * 128;

  const int tid = threadIdx.x;
  const int lane = tid & 63;
  const int wv = tid >> 6;
  const int wr = wv >> 1, wc = wv & 1;
  const int l15 = lane & 15, kg = lane >> 4;

  f32x4 acc[4][4];
#pragma unroll
  for (int mi = 0; mi < 4; ++mi)
#pragma unroll
    for (int ni = 0; ni < 4; ++ni) {
      f32x4 z = {0.f, 0.f, 0.f, 0.f};
      acc[mi][ni] = z;
    }

  auto stage = [&](const unsigned short* src, int row0, int k0, unsigned short* lds) {
#pragma unroll
    for (int j = 0; j < 2; ++j) {
      const int chunk = (wv * 2 + j) * 64 + lane;   // 512 x 16B per tile
      const int r = chunk >> 2, kc = chunk & 3;
      const unsigned short* g = src + (size_t)(row0 + r) * 1024 + k0 + kc * 8;
      __builtin_amdgcn_global_load_lds((gas_ptr)g, (las_ptr)(lds + chunk * 8), 16, 0, 0);
    }
  };

  stage(A, m0, 0, Al[0]);
  stage(Bt, n0, 0, Bl[0]);
  __syncthreads();

  int buf = 0;
  for (int kt = 0; kt < 32; ++kt) {
    if (kt < 31) {
      stage(A, m0, (kt + 1) * 32, Al[buf ^ 1]);
      stage(Bt, n0, (kt + 1) * 32, Bl[buf ^ 1]);
    }
    bf16x8 a[4], b[4];
#pragma unroll
    for (int mi = 0; mi < 4; ++mi)
      a[mi] = *(const bf16x8*)&Al[buf][(wr * 64 + mi * 16 + l15) * 32 + kg * 8];
#pragma unroll
    for (int ni = 0; ni < 4; ++ni)
      b[ni] = *(const bf16x8*)&Bl[buf][(wc * 64 + ni * 16 + l15) * 32 + kg * 8];
#pragma unroll
    for (int mi = 0; mi < 4; ++mi)
#pragma unroll
      for (int ni = 0; ni < 4; ++ni)
        acc[mi][ni] = __builtin_amdgcn_mfma_f32_16x16x32_bf16(a[mi], b[ni], acc[mi][ni], 0, 0, 0);
    __syncthreads();  // drains vmcnt (stage kt+1 done) + protects buf reuse
    buf ^= 1;
  }

#pragma unroll
  for (int ni = 0; ni < 4; ++ni) {
    const int ocol = n0 + wc * 64 + ni * 16 + l15;   // C/D: col = lane&15
    const float bv = decb[ocol];
#pragma unroll
    for (int mi = 0; mi < 4; ++mi) {
      const int orow = m0 + wr * 64 + mi * 16 + kg * 4;  // row = (lane>>4)*4 + reg
#pragma unroll
      for (int r = 0; r < 4; ++r)
        out[(size_t)(orow + r) * 32000 + ocol] = acc[mi][ni][r] + bv;
    }
  }
}

extern "C" void kernel_launch(void* const* d_in, const int* in_sizes, int n_in,
                              void* d_out, int out_size, void* d_ws, size_t ws_size,
                              hipStream_t stream) {
  (void)in_sizes; (void)n_in; (void)out_size; (void)ws_size;
  const int* tokens  = (const int*)d_in[0];
  const float* h0_in = (const float*)d_in[1];
  const float* c0_in = (const float*)d_in[2];
  const float* etab  = (const float*)d_in[3];
  const float* lstmW = (const float*)d_in[4];
  const float* lstmb = (const float*)d_in[5];
  const float* decW  = (const float*)d_in[6];
  const float* decb  = (const float*)d_in[7];
  float* out = (float*)d_out;

  char* ws = (char*)d_ws;
  unsigned short* hseq = (unsigned short*)(ws + 0);          // 8,388,608 B
  unsigned short* Wt   = (unsigned short*)(ws + 8388608);    // 65,536,000 B
  float* h0buf = (float*)(ws + 73924608);                    // 262,144 B
  float* h1buf = (float*)(ws + 74186752);                    // 262,144 B
  float* c0s   = (float*)(ws + 74448896);                    // 131,072 B
  float* c1s   = (float*)(ws + 74579968);                    // 131,072 B
  int* bar     = (int*)(ws + 74711040);                      // 8 B

  init_kernel<<<32, 256, 0, stream>>>(h0_in, c0_in, h0buf, h1buf, c0s, c1s, bar);
  transpose_decw_kernel<<<8000, 256, 0, stream>>>(decW, Wt);
  lstm_seq_kernel<<<512, 256, 65536, stream>>>(tokens, etab, lstmW, lstmb,
                                               h0buf, h1buf, c0s, c1s, hseq,
                                               out + 131072000, bar);
  decoder_kernel<<<8000, 256, 0, stream>>>(hseq, Wt, decb, out);
}

// Round 2
// 16240.862 us; speedup vs baseline: 2.4626x; 2.4626x over previous
//
#include <hip/hip_runtime.h>

typedef __attribute__((ext_vector_type(8))) short bf16x8;
typedef __attribute__((ext_vector_type(4))) float f32x4;
typedef __attribute__((ext_vector_type(2))) float f32x2;
typedef const __attribute__((address_space(1))) void* gas_ptr;
typedef __attribute__((address_space(3))) void* las_ptr;

__device__ __forceinline__ unsigned short f2bf(float f) {
  unsigned int u = __float_as_uint(f);
  return (unsigned short)((u + 0x7fffu + ((u >> 16) & 1u)) >> 16);  // RNE
}
__device__ __forceinline__ float bflo(unsigned int u) { return __uint_as_float(u << 16); }
__device__ __forceinline__ float bfhi(unsigned int u) { return __uint_as_float(u & 0xffff0000u); }
__device__ __forceinline__ unsigned int cvt_pk_bf16(float a, float b) {
  unsigned int r;
  asm volatile("v_cvt_pk_bf16_f32 %0, %1, %2" : "=v"(r) : "v"(a), "v"(b));
  return r;
}
__device__ __forceinline__ float sigm(float x) { return 1.0f / (1.0f + __expf(-x)); }

// ---------------- two-level grid barrier: 16 leaf counters (128B apart) + master ----------------
__device__ __forceinline__ void gbar2(int* bars, int target, int bid) {
  __syncthreads();
  if (threadIdx.x == 0) {
    __threadfence();  // agent-scope release of this block's prior stores
    int* leaf  = bars + (bid & 15) * 32;
    int* mcnt  = bars + 512;
    int* sense = bars + 640;
    if (__hip_atomic_fetch_add(leaf, 1, __ATOMIC_ACQ_REL, __HIP_MEMORY_SCOPE_AGENT) == 31) {
      __hip_atomic_store(leaf, 0, __ATOMIC_RELAXED, __HIP_MEMORY_SCOPE_AGENT);
      if (__hip_atomic_fetch_add(mcnt, 1, __ATOMIC_ACQ_REL, __HIP_MEMORY_SCOPE_AGENT) == 15) {
        __hip_atomic_store(mcnt, 0, __ATOMIC_RELAXED, __HIP_MEMORY_SCOPE_AGENT);
        __hip_atomic_store(sense, target, __ATOMIC_RELEASE, __HIP_MEMORY_SCOPE_AGENT);
      }
    }
    while (__hip_atomic_load(sense, __ATOMIC_ACQUIRE, __HIP_MEMORY_SCOPE_AGENT) != target)
      __builtin_amdgcn_s_sleep(1);
    __threadfence();  // acquire side
  }
  __syncthreads();
}

// ---------------- K1: copy h0/c0 into double-buffered state, zero barrier ----------------
__global__ __launch_bounds__(256) void init_kernel(
    const float* __restrict__ h0_in, const float* __restrict__ c0_in,
    float* __restrict__ h0buf, float* __restrict__ h1buf,
    float* __restrict__ c0s, float* __restrict__ c1s, int* __restrict__ bar)
{
  int j = blockIdx.x * 256 + threadIdx.x;  // 0..8191
  if (j < 768) bar[j] = 0;
#pragma unroll
  for (int q = 0; q < 4; ++q) {
    int f = (j + q * 8192) * 4;  // fp32 index, 0..131068
    if (f < 32768) {                       // layer0 h -> h0buf slot0
      *(float4*)(h0buf + f) = *(const float4*)(h0_in + f);
    } else if (f < 65536) {                // layer1 h -> h1buf slot1 (== offset 32768)
      *(float4*)(h1buf + f) = *(const float4*)(h0_in + f);
    } else if (f < 98304) {                // layer0 c
      *(float4*)(c0s + (f - 65536)) = *(const float4*)(c0_in + (f - 65536));
    } else {                               // layer1 c
      *(float4*)(c1s + (f - 98304)) = *(const float4*)(c0_in + (f - 65536));
    }
  }
}

// ---------------- K2: lstm_W [2][2048][4096] f32 -> per-block LDS images, bf16 ----------------
// Image for block b = layer*256 + ublk (u0 = ublk*4): 16 segments (ksec) x 4128 B.
// Segment: 64 kpair-rows x 64 B; row = 16 cols x u32{bf16 even-k, bf16 odd-k}; col c = gate*4+uo.
// +32B/segment pad makes ksec groups land in distinct bank windows (2-way max on ds_read_b128).
__global__ __launch_bounds__(256) void reorg_lstm_w(
    const float* __restrict__ W, char* __restrict__ wimg)
{
  __shared__ float tile[128 * 132];
  const int bid = blockIdx.x;          // 1024 = 2 layers x 16 kb x 32 cb
  const int l  = bid >> 9;
  const int kb = (bid >> 5) & 15;
  const int cb = bid & 31;
  const int tid = threadIdx.x;
  const float* Wl = W + (size_t)l * 2048 * 4096 + (size_t)kb * 128 * 4096;
  // load 128k x (4 gates x 32 cols) fp32, coalesced
#pragma unroll
  for (int i = 0; i < 16; ++i) {
    const int flat = i * 256 + tid;        // 0..4095
    const int kr = flat >> 5;              // 0..127
    const int c4 = (flat & 31) * 4;        // 0..124
    const int g = c4 >> 5, gc = c4 & 31;
    *(float4*)(tile + kr * 132 + c4) =
        *(const float4*)(Wl + (size_t)kr * 4096 + g * 1024 + cb * 32 + gc);
  }
  __syncthreads();
  // write 8 images x 64 kpair-rows x 64 B, coalesced
#pragma unroll
  for (int i = 0; i < 2; ++i) {
    const int r2 = i * 256 + tid;          // 0..511
    const int ib = r2 >> 6;                // 0..7
    const int kp = r2 & 63;
    const int b = l * 256 + cb * 8 + ib;
    char* dst = wimg + (size_t)b * 66048 + kb * 4128 + kp * 64;
    uint4 u[4];
#pragma unroll
    for (int c = 0; c < 16; ++c) {
      const int cl = (c >> 2) * 32 + ib * 4 + (c & 3);
      const float v0 = tile[(kp * 2 + 0) * 132 + cl];
      const float v1 = tile[(kp * 2 + 1) * 132 + cl];
      ((unsigned int*)u)[c] = cvt_pk_bf16(v0, v1);
    }
#pragma unroll
    for (int m = 0; m < 4; ++m) *(uint4*)(dst + m * 16) = u[m];
  }
}

// ---------------- K3: pipelined 2-layer LSTM scan, weights LDS-resident ----------------
// 512 blocks: layer = bid>>8, u0 = (bid&255)*4 (16 gate cols). 128+1 phases, grid barrier each.
// Thread map: ksec = tid>>4 (k-slice of 128), bg = (tid>>2)&3 (8 rows), cg = tid&3 (4 cols).
// Inner: v_pk_fma_f32 over even/odd-k pairs; x fp32 from global; W bf16 from LDS.
__global__ __launch_bounds__(256, 2) void lstm_seq_kernel(
    const int* __restrict__ tokens, const float* __restrict__ etab,
    const char* __restrict__ wimg, const float* __restrict__ bias,
    float* __restrict__ h0buf, float* __restrict__ h1buf,
    float* __restrict__ c0s, float* __restrict__ c1s,
    unsigned short* __restrict__ hseq,
    float* __restrict__ out_tail, int* __restrict__ bar)
{
  __shared__ char smem[79872];             // [0,66048) W image; [66048,75264) red; [75264,..) gates
  float* red  = (float*)(smem + 66048);    // [4 waves][16 pos][36]
  float* glds = (float*)(smem + 75264);    // [32][36]

  const int tid = threadIdx.x;
  const int bid = blockIdx.x;
  const int layer = bid >> 8;
  const int u0 = (bid & 255) * 4;
  const float* bl = bias + layer * 4096;
  float* hbuf = layer ? h1buf : h0buf;
  float* cst  = layer ? c1s : c0s;

  const int ksec = tid >> 4;
  const int pos = tid & 15;
  const int bg = pos >> 2;      // rows bg*8 .. +7
  const int cg = pos & 3;       // cols cg*4 .. +3
  const int wave = tid >> 6;
  const int lane = tid & 63;
  const int nblk = (int)gridDim.x;
  (void)nblk;

  // ---- one-time: stage this block's weight image into LDS (linear, 16B chunks) ----
  {
    const char* img = wimg + (size_t)bid * 66048;
#pragma unroll 1
    for (int i = 0; i < 16; ++i) {
      const int chunk = i * 256 + tid;
      __builtin_amdgcn_global_load_lds((gas_ptr)(img + (size_t)chunk * 16),
                                       (las_ptr)(smem + chunk * 16), 16, 0, 0);
    }
    if (tid < 32) {
      const int chunk = 4096 + tid;
      __builtin_amdgcn_global_load_lds((gas_ptr)(img + (size_t)chunk * 16),
                                       (las_ptr)(smem + chunk * 16), 16, 0, 0);
    }
  }
  asm volatile("s_waitcnt vmcnt(0)");
  __syncthreads();

  const char* wb = smem + ksec * 4128 + cg * 16;
  const bool low = ksec < 8;
  const int kof = ksec * 128 - (low ? 0 : 1024);

  for (int p = 0; p <= 128; ++p) {
    const bool active = layer ? (p >= 1) : (p < 128);
    if (active) {
      const int t = layer ? (p - 1) : p;
      // x row pointers: layer0 low=emb gather, layer0 high=h0(prev); layer1 low=h0(cur), high=h1(prev)
      const float* xr[8];
      {
        const float* hsrc = (layer == 0 || low) ? (h0buf + (p & 1) * 32768)
                                                : (h1buf + (p & 1) * 32768);
#pragma unroll
        for (int i = 0; i < 8; ++i) {
          const int r = bg * 8 + i;
          if (layer == 0 && low)
            xr[i] = etab + (size_t)tokens[t * 32 + r] * 1024 + kof;
          else
            xr[i] = hsrc + r * 1024 + kof;
        }
      }

      f32x2 acc[8][4];
#pragma unroll
      for (int i = 0; i < 8; ++i)
#pragma unroll
        for (int j = 0; j < 4; ++j) { f32x2 z = {0.f, 0.f}; acc[i][j] = z; }

#pragma unroll 2
      for (int kk4 = 0; kk4 < 32; ++kk4) {
        f32x4 xv[8];
#pragma unroll
        for (int i = 0; i < 8; ++i) xv[i] = *(const f32x4*)(xr[i] + kk4 * 4);
        const uint4 wu0 = *(const uint4*)(wb + kk4 * 128);
        const uint4 wu1 = *(const uint4*)(wb + kk4 * 128 + 64);
        f32x2 wp0[4], wp1[4];
        wp0[0] = f32x2{bflo(wu0.x), bfhi(wu0.x)};
        wp0[1] = f32x2{bflo(wu0.y), bfhi(wu0.y)};
        wp0[2] = f32x2{bflo(wu0.z), bfhi(wu0.z)};
        wp0[3] = f32x2{bflo(wu0.w), bfhi(wu0.w)};
        wp1[0] = f32x2{bflo(wu1.x), bfhi(wu1.x)};
        wp1[1] = f32x2{bflo(wu1.y), bfhi(wu1.y)};
        wp1[2] = f32x2{bflo(wu1.z), bfhi(wu1.z)};
        wp1[3] = f32x2{bflo(wu1.w), bfhi(wu1.w)};
#pragma unroll
        for (int i = 0; i < 8; ++i) {
          const f32x2 xp0 = __builtin_shufflevector(xv[i], xv[i], 0, 1);
          const f32x2 xp1 = __builtin_shufflevector(xv[i], xv[i], 2, 3);
#pragma unroll
          for (int j = 0; j < 4; ++j) {
            acc[i][j] = __builtin_elementwise_fma(xp0, wp0[j], acc[i][j]);
            acc[i][j] = __builtin_elementwise_fma(xp1, wp1[j], acc[i][j]);
          }
        }
      }

      // merge even/odd + in-wave butterfly over the 4 ksec of this wave
      float m[8][4];
#pragma unroll
      for (int i = 0; i < 8; ++i)
#pragma unroll
        for (int j = 0; j < 4; ++j) {
          float s = acc[i][j][0] + acc[i][j][1];
          s += __shfl_xor(s, 16, 64);
          s += __shfl_xor(s, 32, 64);
          m[i][j] = s;
        }
      if (lane < 16) {
        float* rp = red + wave * 576 + lane * 36;
#pragma unroll
        for (int i = 0; i < 8; ++i)
          *(f32x4*)(rp + i * 4) = f32x4{m[i][0], m[i][1], m[i][2], m[i][3]};
      }
      __syncthreads();
      // final 4-way reduce + bias -> gates LDS (2 outputs per thread)
      {
        const int b = tid >> 3;
        const int c = (tid & 7) * 2;
        const int posr = (b >> 3) * 4 + (c >> 2);
        const int v = (b & 7) * 4 + (c & 3);
        float s0 = 0.f, s1 = 0.f;
#pragma unroll
        for (int w = 0; w < 4; ++w) {
          const float* rp = red + w * 576 + posr * 36 + v;
          s0 += rp[0];
          s1 += rp[1];
        }
        const int g = c >> 2, uo = c & 3;
        s0 += bl[g * 1024 + u0 + uo];
        s1 += bl[g * 1024 + u0 + uo + 1];
        glds[b * 36 + c] = s0;
        glds[b * 36 + c + 1] = s1;
      }
      __syncthreads();
      // elementwise cell update: 128 threads = 32b x 4 units
      if (tid < 128) {
        const int b = tid >> 2, uo = tid & 3, u = u0 + uo;
        const float gi = glds[b * 36 + 0 + uo];
        const float gj = glds[b * 36 + 4 + uo];
        const float gf = glds[b * 36 + 8 + uo];
        const float go = glds[b * 36 + 12 + uo];
        const float cold = cst[b * 1024 + u];
        const float cn = cold * sigm(gf) + sigm(gi) * tanhf(gj);
        const float hn = tanhf(cn) * sigm(go);
        cst[b * 1024 + u] = cn;
        hbuf[((p + 1) & 1) * 32768 + b * 1024 + u] = hn;
        if (layer) hseq[(size_t)t * 32768 + b * 1024 + u] = f2bf(hn);
        if (t == 127) {
          out_tail[layer * 32768 + b * 1024 + u] = hn;           // h_last
          out_tail[65536 + layer * 32768 + b * 1024 + u] = cn;   // c_last
        }
      }
    }
    if (p < 128) gbar2(bar, p + 1, bid);
  }
}

// ---------------- K4: dec_W [1024][32000] f32 -> Wt [32000][1024] bf16 ----------------
__global__ __launch_bounds__(256) void transpose_decw_kernel(
    const float* __restrict__ decW, unsigned short* __restrict__ Wt)
{
  __shared__ float tile[64 * 68];
  const int bid = blockIdx.x;         // 8000 = 16 k-tiles x 500 n-tiles
  const int k0 = (bid & 15) * 64;
  const int n0 = (bid >> 4) * 64;
  const int tid = threadIdx.x;
  {
    const int kl = tid >> 4, c4 = (tid & 15) * 4;
#pragma unroll
    for (int i = 0; i < 4; ++i) {
      const int kr = kl + 16 * i;
      *(float4*)(tile + kr * 68 + c4) =
          *(const float4*)(decW + (size_t)(k0 + kr) * 32000 + n0 + c4);
    }
  }
  __syncthreads();
  {
    const int nl = tid >> 3, kc = (tid & 7) * 8;
#pragma unroll
    for (int h2 = 0; h2 < 2; ++h2) {
      const int n = nl + 32 * h2;
      float tv[8];
#pragma unroll
      for (int q = 0; q < 8; ++q) tv[q] = tile[(kc + q) * 68 + n];
      uint4 u;
      u.x = cvt_pk_bf16(tv[0], tv[1]);
      u.y = cvt_pk_bf16(tv[2], tv[3]);
      u.z = cvt_pk_bf16(tv[4], tv[5]);
      u.w = cvt_pk_bf16(tv[6], tv[7]);
      *(uint4*)(Wt + (size_t)(n0 + n) * 1024 + k0 + kc) = u;
    }
  }
}

// ---------------- K5: decoder bf16 MFMA GEMM, 128x128 tile, BK=32, double-buffered ----------------
__global__ __launch_bounds__(256) void decoder_kernel(
    const unsigned short* __restrict__ A,   // hseq  [4096][1024] bf16
    const unsigned short* __restrict__ Bt,  // Wt    [32000][1024] bf16 (dec_W^T)
    const float* __restrict__ decb,
    float* __restrict__ out)                // [4096][32000] f32
{
  __shared__ unsigned short Al[2][128 * 32];
  __shared__ unsigned short Bl[2][128 * 32];

  const int bid = blockIdx.x;
  const int swz = (bid & 7) * 1000 + (bid >> 3);  // XCD-contiguous tile chunks (8000 % 8 == 0)
  const int mt = swz / 250, nt = swz % 250;
  const int m0 = mt * 128, n0 = nt * 128;

  const int tid = threadIdx.x;
  const int lane = tid & 63;
  const int wv = tid >> 6;
  const int wr = wv >> 1, wc = wv & 1;
  const int l15 = lane & 15, kg = lane >> 4;

  f32x4 acc[4][4];
#pragma unroll
  for (int mi = 0; mi < 4; ++mi)
#pragma unroll
    for (int ni = 0; ni < 4; ++ni) {
      f32x4 z = {0.f, 0.f, 0.f, 0.f};
      acc[mi][ni] = z;
    }

  auto stage = [&](const unsigned short* src, int row0, int k0, unsigned short* lds) {
#pragma unroll
    for (int j = 0; j < 2; ++j) {
      const int chunk = (wv * 2 + j) * 64 + lane;   // 512 x 16B per tile
      const int r = chunk >> 2, kc = chunk & 3;
      const unsigned short* g = src + (size_t)(row0 + r) * 1024 + k0 + kc * 8;
      __builtin_amdgcn_global_load_lds((gas_ptr)g, (las_ptr)(lds + chunk * 8), 16, 0, 0);
    }
  };

  stage(A, m0, 0, Al[0]);
  stage(Bt, n0, 0, Bl[0]);
  __syncthreads();

  int buf = 0;
  for (int kt = 0; kt < 32; ++kt) {
    if (kt < 31) {
      stage(A, m0, (kt + 1) * 32, Al[buf ^ 1]);
      stage(Bt, n0, (kt + 1) * 32, Bl[buf ^ 1]);
    }
    bf16x8 a[4], b[4];
#pragma unroll
    for (int mi = 0; mi < 4; ++mi)
      a[mi] = *(const bf16x8*)&Al[buf][(wr * 64 + mi * 16 + l15) * 32 + kg * 8];
#pragma unroll
    for (int ni = 0; ni < 4; ++ni)
      b[ni] = *(const bf16x8*)&Bl[buf][(wc * 64 + ni * 16 + l15) * 32 + kg * 8];
#pragma unroll
    for (int mi = 0; mi < 4; ++mi)
#pragma unroll
      for (int ni = 0; ni < 4; ++ni)
        acc[mi][ni] = __builtin_amdgcn_mfma_f32_16x16x32_bf16(a[mi], b[ni], acc[mi][ni], 0, 0, 0);
    __syncthreads();  // drains vmcnt (stage kt+1 done) + protects buf reuse
    buf ^= 1;
  }

#pragma unroll
  for (int ni = 0; ni < 4; ++ni) {
    const int ocol = n0 + wc * 64 + ni * 16 + l15;   // C/D: col = lane&15
    const float bv = decb[ocol];
#pragma unroll
    for (int mi = 0; mi < 4; ++mi) {
      const int orow = m0 + wr * 64 + mi * 16 + kg * 4;  // row = (lane>>4)*4 + reg
#pragma unroll
      for (int r = 0; r < 4; ++r)
        out[(size_t)(orow + r) * 32000 + ocol] = acc[mi][ni][r] + bv;
    }
  }
}

extern "C" void kernel_launch(void* const* d_in, const int* in_sizes, int n_in,
                              void* d_out, int out_size, void* d_ws, size_t ws_size,
                              hipStream_t stream) {
  (void)in_sizes; (void)n_in; (void)out_size; (void)ws_size;
  const int* tokens  = (const int*)d_in[0];
  const float* h0_in = (const float*)d_in[1];
  const float* c0_in = (const float*)d_in[2];
  const float* etab  = (const float*)d_in[3];
  const float* lstmW = (const float*)d_in[4];
  const float* lstmb = (const float*)d_in[5];
  const float* decW  = (const float*)d_in[6];
  const float* decb  = (const float*)d_in[7];
  float* out = (float*)d_out;

  char* ws = (char*)d_ws;
  unsigned short* hseq = (unsigned short*)(ws + 0);          // 8,388,608 B
  char* img            = ws + 8388608;                       // 33,816,576 B (lstm phase)
  unsigned short* Wt   = (unsigned short*)(ws + 8388608);    // 65,536,000 B (decoder phase, after lstm)
  float* h0buf = (float*)(ws + 73924608);                    // 262,144 B
  float* h1buf = (float*)(ws + 74186752);                    // 262,144 B
  float* c0s   = (float*)(ws + 74448896);                    // 131,072 B
  float* c1s   = (float*)(ws + 74579968);                    // 131,072 B
  int* bar     = (int*)(ws + 74711040);                      // 3,072 B (768 ints)

  init_kernel<<<32, 256, 0, stream>>>(h0_in, c0_in, h0buf, h1buf, c0s, c1s, bar);
  reorg_lstm_w<<<1024, 256, 0, stream>>>(lstmW, img);
  lstm_seq_kernel<<<512, 256, 0, stream>>>(tokens, etab, img, lstmb,
                                           h0buf, h1buf, c0s, c1s, hseq,
                                           out + 131072000, bar);
  transpose_decw_kernel<<<8000, 256, 0, stream>>>(decW, Wt);
  decoder_kernel<<<8000, 256, 0, stream>>>(hseq, Wt, decb, out);
}

// Round 3
// 16235.023 us; speedup vs baseline: 2.4635x; 1.0004x over previous
//
#include <hip/hip_runtime.h>

typedef __attribute__((ext_vector_type(8))) short bf16x8;
typedef __attribute__((ext_vector_type(4))) float f32x4;
typedef __attribute__((ext_vector_type(2))) float f32x2;
typedef const __attribute__((address_space(1))) void* gas_ptr;
typedef __attribute__((address_space(3))) void* las_ptr;

__device__ __forceinline__ unsigned short f2bf(float f) {
  unsigned int u = __float_as_uint(f);
  return (unsigned short)((u + 0x7fffu + ((u >> 16) & 1u)) >> 16);  // RNE
}
__device__ __forceinline__ float bflo(unsigned int u) { return __uint_as_float(u << 16); }
__device__ __forceinline__ float bfhi(unsigned int u) { return __uint_as_float(u & 0xffff0000u); }
__device__ __forceinline__ unsigned int cvt_pk_bf16(float a, float b) {
  unsigned int r;
  asm volatile("v_cvt_pk_bf16_f32 %0, %1, %2" : "=v"(r) : "v"(a), "v"(b));
  return r;
}
__device__ __forceinline__ float sigm(float x) { return 1.0f / (1.0f + __expf(-x)); }

// ---------------- two-level grid barrier: 16 leaf counters (128B apart) + master ----------------
__device__ __forceinline__ void gbar2(int* bars, int target, int bid) {
  __syncthreads();
  if (threadIdx.x == 0) {
    __threadfence();  // agent-scope release of this block's prior stores
    int* leaf  = bars + (bid & 15) * 32;
    int* mcnt  = bars + 512;
    int* sense = bars + 640;
    if (__hip_atomic_fetch_add(leaf, 1, __ATOMIC_ACQ_REL, __HIP_MEMORY_SCOPE_AGENT) == 31) {
      __hip_atomic_store(leaf, 0, __ATOMIC_RELAXED, __HIP_MEMORY_SCOPE_AGENT);
      if (__hip_atomic_fetch_add(mcnt, 1, __ATOMIC_ACQ_REL, __HIP_MEMORY_SCOPE_AGENT) == 15) {
        __hip_atomic_store(mcnt, 0, __ATOMIC_RELAXED, __HIP_MEMORY_SCOPE_AGENT);
        __hip_atomic_store(sense, target, __ATOMIC_RELEASE, __HIP_MEMORY_SCOPE_AGENT);
      }
    }
    while (__hip_atomic_load(sense, __ATOMIC_ACQUIRE, __HIP_MEMORY_SCOPE_AGENT) != target)
      __builtin_amdgcn_s_sleep(1);
    __threadfence();  // acquire side
  }
  __syncthreads();
}

// ---------------- K1: copy h0/c0 into double-buffered state, zero barrier ----------------
__global__ __launch_bounds__(256) void init_kernel(
    const float* __restrict__ h0_in, const float* __restrict__ c0_in,
    float* __restrict__ h0buf, float* __restrict__ h1buf,
    float* __restrict__ c0s, float* __restrict__ c1s, int* __restrict__ bar)
{
  int j = blockIdx.x * 256 + threadIdx.x;  // 0..8191
  if (j < 768) bar[j] = 0;
#pragma unroll
  for (int q = 0; q < 4; ++q) {
    int f = (j + q * 8192) * 4;  // fp32 index, 0..131068
    if (f < 32768) {                       // layer0 h -> h0buf slot0
      *(float4*)(h0buf + f) = *(const float4*)(h0_in + f);
    } else if (f < 65536) {                // layer1 h -> h1buf slot1 (== offset 32768)
      *(float4*)(h1buf + f) = *(const float4*)(h0_in + f);
    } else if (f < 98304) {                // layer0 c
      *(float4*)(c0s + (f - 65536)) = *(const float4*)(c0_in + (f - 65536));
    } else {                               // layer1 c
      *(float4*)(c1s + (f - 98304)) = *(const float4*)(c0_in + (f - 65536));
    }
  }
}

// ---------------- K2: lstm_W [2][2048][4096] f32 -> per-block LDS images, bf16 ----------------
// Image for block b = layer*256 + ublk (u0 = ublk*4): 16 segments (ksec) x 4128 B.
// Segment: 64 kpair-rows x 64 B; row = 16 cols x u32{bf16 even-k, bf16 odd-k}; col c = gate*4+uo.
// +32B/segment pad makes ksec groups land in distinct bank windows (2-way max on ds_read_b128).
__global__ __launch_bounds__(256) void reorg_lstm_w(
    const float* __restrict__ W, char* __restrict__ wimg)
{
  __shared__ float tile[128 * 132];
  const int bid = blockIdx.x;          // 1024 = 2 layers x 16 kb x 32 cb
  const int l  = bid >> 9;
  const int kb = (bid >> 5) & 15;
  const int cb = bid & 31;
  const int tid = threadIdx.x;
  const float* Wl = W + (size_t)l * 2048 * 4096 + (size_t)kb * 128 * 4096;
  // load 128k x (4 gates x 32 cols) fp32, coalesced
#pragma unroll
  for (int i = 0; i < 16; ++i) {
    const int flat = i * 256 + tid;        // 0..4095
    const int kr = flat >> 5;              // 0..127
    const int c4 = (flat & 31) * 4;        // 0..124
    const int g = c4 >> 5, gc = c4 & 31;
    *(float4*)(tile + kr * 132 + c4) =
        *(const float4*)(Wl + (size_t)kr * 4096 + g * 1024 + cb * 32 + gc);
  }
  __syncthreads();
  // write 8 images x 64 kpair-rows x 64 B, coalesced
#pragma unroll
  for (int i = 0; i < 2; ++i) {
    const int r2 = i * 256 + tid;          // 0..511
    const int ib = r2 >> 6;                // 0..7
    const int kp = r2 & 63;
    const int b = l * 256 + cb * 8 + ib;
    char* dst = wimg + (size_t)b * 66048 + kb * 4128 + kp * 64;
    uint4 u[4];
#pragma unroll
    for (int c = 0; c < 16; ++c) {
      const int cl = (c >> 2) * 32 + ib * 4 + (c & 3);
      const float v0 = tile[(kp * 2 + 0) * 132 + cl];
      const float v1 = tile[(kp * 2 + 1) * 132 + cl];
      ((unsigned int*)u)[c] = cvt_pk_bf16(v0, v1);
    }
#pragma unroll
    for (int m = 0; m < 4; ++m) *(uint4*)(dst + m * 16) = u[m];
  }
}

// ---------------- K3: pipelined 2-layer LSTM scan, weights LDS-resident ----------------
// 512 blocks: layer = bid>>8, u0 = (bid&255)*4 (16 gate cols). 128+1 phases, grid barrier each.
// Thread map: ksec = tid>>4 (k-slice of 128), bg = (tid>>2)&3 (8 rows), cg = tid&3 (4 cols).
// Inner: v_pk_fma_f32 over even/odd-k pairs; x fp32 from global; W bf16 from LDS.
__global__ __launch_bounds__(256, 2) void lstm_seq_kernel(
    const int* __restrict__ tokens, const float* __restrict__ etab,
    const char* __restrict__ wimg, const float* __restrict__ bias,
    float* __restrict__ h0buf, float* __restrict__ h1buf,
    float* __restrict__ c0s, float* __restrict__ c1s,
    unsigned short* __restrict__ hseq,
    float* __restrict__ out_tail, int* __restrict__ bar)
{
  __shared__ char smem[79872];             // [0,66048) W image; [66048,75264) red; [75264,..) gates
  float* red  = (float*)(smem + 66048);    // [4 waves][16 pos][36]
  float* glds = (float*)(smem + 75264);    // [32][36]

  const int tid = threadIdx.x;
  const int bid = blockIdx.x;
  const int layer = bid >> 8;
  const int u0 = (bid & 255) * 4;
  const float* bl = bias + layer * 4096;
  float* hbuf = layer ? h1buf : h0buf;
  float* cst  = layer ? c1s : c0s;

  const int ksec = tid >> 4;
  const int pos = tid & 15;
  const int bg = pos >> 2;      // rows bg*8 .. +7
  const int cg = pos & 3;       // cols cg*4 .. +3
  const int wave = tid >> 6;
  const int lane = tid & 63;
  const int nblk = (int)gridDim.x;
  (void)nblk;

  // ---- one-time: stage this block's weight image into LDS (linear, 16B chunks) ----
  {
    const char* img = wimg + (size_t)bid * 66048;
#pragma unroll 1
    for (int i = 0; i < 16; ++i) {
      const int chunk = i * 256 + tid;
      __builtin_amdgcn_global_load_lds((gas_ptr)(img + (size_t)chunk * 16),
                                       (las_ptr)(smem + chunk * 16), 16, 0, 0);
    }
    if (tid < 32) {
      const int chunk = 4096 + tid;
      __builtin_amdgcn_global_load_lds((gas_ptr)(img + (size_t)chunk * 16),
                                       (las_ptr)(smem + chunk * 16), 16, 0, 0);
    }
  }
  asm volatile("s_waitcnt vmcnt(0)");
  __syncthreads();

  const char* wb = smem + ksec * 4128 + cg * 16;
  const bool low = ksec < 8;
  const int kof = ksec * 128 - (low ? 0 : 1024);

  for (int p = 0; p <= 128; ++p) {
    const bool active = layer ? (p >= 1) : (p < 128);
    if (active) {
      const int t = layer ? (p - 1) : p;
      // x row pointers: layer0 low=emb gather, layer0 high=h0(prev); layer1 low=h0(cur), high=h1(prev)
      const float* xr[8];
      {
        const float* hsrc = (layer == 0 || low) ? (h0buf + (p & 1) * 32768)
                                                : (h1buf + (p & 1) * 32768);
#pragma unroll
        for (int i = 0; i < 8; ++i) {
          const int r = bg * 8 + i;
          if (layer == 0 && low)
            xr[i] = etab + (size_t)tokens[t * 32 + r] * 1024 + kof;
          else
            xr[i] = hsrc + r * 1024 + kof;
        }
      }

      f32x2 acc[8][4];
#pragma unroll
      for (int i = 0; i < 8; ++i)
#pragma unroll
        for (int j = 0; j < 4; ++j) { f32x2 z = {0.f, 0.f}; acc[i][j] = z; }

#pragma unroll 2
      for (int kk4 = 0; kk4 < 32; ++kk4) {
        f32x4 xv[8];
#pragma unroll
        for (int i = 0; i < 8; ++i) xv[i] = *(const f32x4*)(xr[i] + kk4 * 4);
        const uint4 wu0 = *(const uint4*)(wb + kk4 * 128);
        const uint4 wu1 = *(const uint4*)(wb + kk4 * 128 + 64);
        f32x2 wp0[4], wp1[4];
        wp0[0] = f32x2{bflo(wu0.x), bfhi(wu0.x)};
        wp0[1] = f32x2{bflo(wu0.y), bfhi(wu0.y)};
        wp0[2] = f32x2{bflo(wu0.z), bfhi(wu0.z)};
        wp0[3] = f32x2{bflo(wu0.w), bfhi(wu0.w)};
        wp1[0] = f32x2{bflo(wu1.x), bfhi(wu1.x)};
        wp1[1] = f32x2{bflo(wu1.y), bfhi(wu1.y)};
        wp1[2] = f32x2{bflo(wu1.z), bfhi(wu1.z)};
        wp1[3] = f32x2{bflo(wu1.w), bfhi(wu1.w)};
#pragma unroll
        for (int i = 0; i < 8; ++i) {
          const f32x2 xp0 = __builtin_shufflevector(xv[i], xv[i], 0, 1);
          const f32x2 xp1 = __builtin_shufflevector(xv[i], xv[i], 2, 3);
#pragma unroll
          for (int j = 0; j < 4; ++j) {
            acc[i][j] = __builtin_elementwise_fma(xp0, wp0[j], acc[i][j]);
            acc[i][j] = __builtin_elementwise_fma(xp1, wp1[j], acc[i][j]);
          }
        }
      }

      // merge even/odd + in-wave butterfly over the 4 ksec of this wave
      float m[8][4];
#pragma unroll
      for (int i = 0; i < 8; ++i)
#pragma unroll
        for (int j = 0; j < 4; ++j) {
          float s = acc[i][j][0] + acc[i][j][1];
          s += __shfl_xor(s, 16, 64);
          s += __shfl_xor(s, 32, 64);
          m[i][j] = s;
        }
      if (lane < 16) {
        float* rp = red + wave * 576 + lane * 36;
#pragma unroll
        for (int i = 0; i < 8; ++i)
          *(f32x4*)(rp + i * 4) = f32x4{m[i][0], m[i][1], m[i][2], m[i][3]};
      }
      __syncthreads();
      // final 4-way reduce + bias -> gates LDS (2 outputs per thread)
      {
        const int b = tid >> 3;
        const int c = (tid & 7) * 2;
        const int posr = (b >> 3) * 4 + (c >> 2);
        const int v = (b & 7) * 4 + (c & 3);
        float s0 = 0.f, s1 = 0.f;
#pragma unroll
        for (int w = 0; w < 4; ++w) {
          const float* rp = red + w * 576 + posr * 36 + v;
          s0 += rp[0];
          s1 += rp[1];
        }
        const int g = c >> 2, uo = c & 3;
        s0 += bl[g * 1024 + u0 + uo];
        s1 += bl[g * 1024 + u0 + uo + 1];
        glds[b * 36 + c] = s0;
        glds[b * 36 + c + 1] = s1;
      }
      __syncthreads();
      // elementwise cell update: 128 threads = 32b x 4 units
      if (tid < 128) {
        const int b = tid >> 2, uo = tid & 3, u = u0 + uo;
        const float gi = glds[b * 36 + 0 + uo];
        const float gj = glds[b * 36 + 4 + uo];
        const float gf = glds[b * 36 + 8 + uo];
        const float go = glds[b * 36 + 12 + uo];
        const float cold = cst[b * 1024 + u];
        const float cn = cold * sigm(gf) + sigm(gi) * tanhf(gj);
        const float hn = tanhf(cn) * sigm(go);
        cst[b * 1024 + u] = cn;
        hbuf[((p + 1) & 1) * 32768 + b * 1024 + u] = hn;
        if (layer) hseq[(size_t)t * 32768 + b * 1024 + u] = f2bf(hn);
        if (t == 127) {
          out_tail[layer * 32768 + b * 1024 + u] = hn;           // h_last
          out_tail[65536 + layer * 32768 + b * 1024 + u] = cn;   // c_last
        }
      }
    }
    if (p < 128) gbar2(bar, p + 1, bid);
  }
}

// ---------------- K4: dec_W [1024][32000] f32 -> Wt [32000][1024] bf16 ----------------
__global__ __launch_bounds__(256) void transpose_decw_kernel(
    const float* __restrict__ decW, unsigned short* __restrict__ Wt)
{
  __shared__ float tile[64 * 68];
  const int bid = blockIdx.x;         // 8000 = 16 k-tiles x 500 n-tiles
  const int k0 = (bid & 15) * 64;
  const int n0 = (bid >> 4) * 64;
  const int tid = threadIdx.x;
  {
    const int kl = tid >> 4, c4 = (tid & 15) * 4;
#pragma unroll
    for (int i = 0; i < 4; ++i) {
      const int kr = kl + 16 * i;
      *(float4*)(tile + kr * 68 + c4) =
          *(const float4*)(decW + (size_t)(k0 + kr) * 32000 + n0 + c4);
    }
  }
  __syncthreads();
  {
    const int nl = tid >> 3, kc = (tid & 7) * 8;
#pragma unroll
    for (int h2 = 0; h2 < 2; ++h2) {
      const int n = nl + 32 * h2;
      float tv[8];
#pragma unroll
      for (int q = 0; q < 8; ++q) tv[q] = tile[(kc + q) * 68 + n];
      uint4 u;
      u.x = cvt_pk_bf16(tv[0], tv[1]);
      u.y = cvt_pk_bf16(tv[2], tv[3]);
      u.z = cvt_pk_bf16(tv[4], tv[5]);
      u.w = cvt_pk_bf16(tv[6], tv[7]);
      *(uint4*)(Wt + (size_t)(n0 + n) * 1024 + k0 + kc) = u;
    }
  }
}

// ---------------- K5: decoder bf16 MFMA GEMM, 128x128 tile, BK=32, double-buffered ----------------
__global__ __launch_bounds__(256) void decoder_kernel(
    const unsigned short* __restrict__ A,   // hseq  [4096][1024] bf16
    const unsigned short* __restrict__ Bt,  // Wt    [32000][1024] bf16 (dec_W^T)
    const float* __restrict__ decb,
    float* __restrict__ out)                // [4096][32000] f32
{
  __shared__ unsigned short Al[2][128 * 32];
  __shared__ unsigned short Bl[2][128 * 32];

  const int bid = blockIdx.x;
  const int swz = (bid & 7) * 1000 + (bid >> 3);  // XCD-contiguous tile chunks (8000 % 8 == 0)
  const int mt = swz / 250, nt = swz % 250;
  const int m0 = mt * 128, n0 = nt * 128;

  const int tid = threadIdx.x;
  const int lane = tid & 63;
  const int wv = tid >> 6;
  const int wr = wv >> 1, wc = wv & 1;
  const int l15 = lane & 15, kg = lane >> 4;

  f32x4 acc[4][4];
#pragma unroll
  for (int mi = 0; mi < 4; ++mi)
#pragma unroll
    for (int ni = 0; ni < 4; ++ni) {
      f32x4 z = {0.f, 0.f, 0.f, 0.f};
      acc[mi][ni] = z;
    }

  auto stage = [&](const unsigned short* src, int row0, int k0, unsigned short* lds) {
#pragma unroll
    for (int j = 0; j < 2; ++j) {
      const int chunk = (wv * 2 + j) * 64 + lane;   // 512 x 16B per tile
      const int r = chunk >> 2, kc = chunk & 3;
      const unsigned short* g = src + (size_t)(row0 + r) * 1024 + k0 + kc * 8;
      __builtin_amdgcn_global_load_lds((gas_ptr)g, (las_ptr)(lds + chunk * 8), 16, 0, 0);
    }
  };

  stage(A, m0, 0, Al[0]);
  stage(Bt, n0, 0, Bl[0]);
  __syncthreads();

  int buf = 0;
  for (int kt = 0; kt < 32; ++kt) {
    if (kt < 31) {
      stage(A, m0, (kt + 1) * 32, Al[buf ^ 1]);
      stage(Bt, n0, (kt + 1) * 32, Bl[buf ^ 1]);
    }
    bf16x8 a[4], b[4];
#pragma unroll
    for (int mi = 0; mi < 4; ++mi)
      a[mi] = *(const bf16x8*)&Al[buf][(wr * 64 + mi * 16 + l15) * 32 + kg * 8];
#pragma unroll
    for (int ni = 0; ni < 4; ++ni)
      b[ni] = *(const bf16x8*)&Bl[buf][(wc * 64 + ni * 16 + l15) * 32 + kg * 8];
#pragma unroll
    for (int mi = 0; mi < 4; ++mi)
#pragma unroll
      for (int ni = 0; ni < 4; ++ni)
        acc[mi][ni] = __builtin_amdgcn_mfma_f32_16x16x32_bf16(a[mi], b[ni], acc[mi][ni], 0, 0, 0);
    __syncthreads();  // drains vmcnt (stage kt+1 done) + protects buf reuse
    buf ^= 1;
  }

#pragma unroll
  for (int ni = 0; ni < 4; ++ni) {
    const int ocol = n0 + wc * 64 + ni * 16 + l15;   // C/D: col = lane&15
    const float bv = decb[ocol];
#pragma unroll
    for (int mi = 0; mi < 4; ++mi) {
      const int orow = m0 + wr * 64 + mi * 16 + kg * 4;  // row = (lane>>4)*4 + reg
#pragma unroll
      for (int r = 0; r < 4; ++r)
        out[(size_t)(orow + r) * 32000 + ocol] = acc[mi][ni][r] + bv;
    }
  }
}

extern "C" void kernel_launch(void* const* d_in, const int* in_sizes, int n_in,
                              void* d_out, int out_size, void* d_ws, size_t ws_size,
                              hipStream_t stream) {
  (void)in_sizes; (void)n_in; (void)out_size; (void)ws_size;
  const int* tokens  = (const int*)d_in[0];
  const float* h0_in = (const float*)d_in[1];
  const float* c0_in = (const float*)d_in[2];
  const float* etab  = (const float*)d_in[3];
  const float* lstmW = (const float*)d_in[4];
  const float* lstmb = (const float*)d_in[5];
  const float* decW  = (const float*)d_in[6];
  const float* decb  = (const float*)d_in[7];
  float* out = (float*)d_out;

  char* ws = (char*)d_ws;
  unsigned short* hseq = (unsigned short*)(ws + 0);          // 8,388,608 B
  char* img            = ws + 8388608;                       // 33,816,576 B (lstm phase)
  unsigned short* Wt   = (unsigned short*)(ws + 8388608);    // 65,536,000 B (decoder phase, after lstm)
  float* h0buf = (float*)(ws + 73924608);                    // 262,144 B
  float* h1buf = (float*)(ws + 74186752);                    // 262,144 B
  float* c0s   = (float*)(ws + 74448896);                    // 131,072 B
  float* c1s   = (float*)(ws + 74579968);                    // 131,072 B
  int* bar     = (int*)(ws + 74711040);                      // 3,072 B (768 ints)

  init_kernel<<<32, 256, 0, stream>>>(h0_in, c0_in, h0buf, h1buf, c0s, c1s, bar);
  reorg_lstm_w<<<1024, 256, 0, stream>>>(lstmW, img);
  lstm_seq_kernel<<<512, 256, 0, stream>>>(tokens, etab, img, lstmb,
                                           h0buf, h1buf, c0s, c1s, hseq,
                                           out + 131072000, bar);
  transpose_decw_kernel<<<8000, 256, 0, stream>>>(decW, Wt);
  decoder_kernel<<<8000, 256, 0, stream>>>(hseq, Wt, decb, out);
}

// Round 4
// 3798.198 us; speedup vs baseline: 10.5299x; 4.2744x over previous
//
#include <hip/hip_runtime.h>

typedef __attribute__((ext_vector_type(8))) short bf16x8;
typedef __attribute__((ext_vector_type(4))) float f32x4;
typedef const __attribute__((address_space(1))) void* gas_ptr;
typedef __attribute__((address_space(3))) void* las_ptr;

__device__ __forceinline__ unsigned short f2bf(float f) {
  unsigned int u = __float_as_uint(f);
  return (unsigned short)((u + 0x7fffu + ((u >> 16) & 1u)) >> 16);  // RNE
}
__device__ __forceinline__ unsigned int cvt_pk_bf16(float a, float b) {
  unsigned int r;
  asm volatile("v_cvt_pk_bf16_f32 %0, %1, %2" : "=v"(r) : "v"(a), "v"(b));
  return r;
}
__device__ __forceinline__ float sigm(float x) { return 1.0f / (1.0f + __expf(-x)); }

// ---- two-level grid barrier; mostly-RELAXED polling (acquire every 8th poll) ----
__device__ __forceinline__ void gbar2(int* bars, int target, int bid) {
  __syncthreads();
  if (threadIdx.x == 0) {
    __threadfence();  // release: h stores -> IF before signaling
    int* leaf  = bars + (bid & 15) * 32;
    int* mcnt  = bars + 512;
    int* sense = bars + 640;
    if (__hip_atomic_fetch_add(leaf, 1, __ATOMIC_ACQ_REL, __HIP_MEMORY_SCOPE_AGENT) == 15) {
      __hip_atomic_store(leaf, 0, __ATOMIC_RELAXED, __HIP_MEMORY_SCOPE_AGENT);
      if (__hip_atomic_fetch_add(mcnt, 1, __ATOMIC_ACQ_REL, __HIP_MEMORY_SCOPE_AGENT) == 15) {
        __hip_atomic_store(mcnt, 0, __ATOMIC_RELAXED, __HIP_MEMORY_SCOPE_AGENT);
        __hip_atomic_store(sense, target, __ATOMIC_RELEASE, __HIP_MEMORY_SCOPE_AGENT);
      }
    }
    int v = __hip_atomic_load(sense, __ATOMIC_RELAXED, __HIP_MEMORY_SCOPE_AGENT);
    int it = 0;
    while (v < target) {
      __builtin_amdgcn_s_sleep(2);
      ++it;
      v = ((it & 7) == 0)
            ? __hip_atomic_load(sense, __ATOMIC_ACQUIRE, __HIP_MEMORY_SCOPE_AGENT)
            : __hip_atomic_load(sense, __ATOMIC_RELAXED, __HIP_MEMORY_SCOPE_AGENT);
    }
    __threadfence();  // acquire: invalidate L1/L2 once before data reads
  }
  __syncthreads();
}

// ---------------- K1: h0 -> bf16 double-buffered state, zero barrier ----------------
__global__ __launch_bounds__(256) void init_kernel(
    const float* __restrict__ h0_in,
    unsigned short* __restrict__ h0buf, unsigned short* __restrict__ h1buf,
    int* __restrict__ bar)
{
  const int j = blockIdx.x * 256 + threadIdx.x;   // 0..32767
  if (j < 768) bar[j] = 0;
  h0buf[j] = f2bf(h0_in[j]);                 // layer0 h -> h0buf slot0
  h1buf[32768 + j] = f2bf(h0_in[32768 + j]); // layer1 h -> h1buf slot1
}

// ---------------- K2: lstm_W -> per-block MFMA-fragment-slot images (bf16) ----------------
// Image for lstm block bid (layer=bid>>7, u0=(bid&127)*8): 8192 slots x 16B, slot
// S = kstep*128 + tn*64 + ksub*16 + row ; content = W[kstep*32+ksub*8 .. +8][gcol]
// as 8 bf16 (k-contiguous), where c = tn*16+row, gcol = (c>>3)*1024 + u0 + (c&7).
__global__ __launch_bounds__(256) void reorg_lstm_w(
    const float* __restrict__ W, char* __restrict__ wimg)
{
  __shared__ float tile[64 * 36];
  const int bid = blockIdx.x;            // 256 = lstm block id
  const int layer = bid >> 7;
  const int u0 = (bid & 127) * 8;
  const int tid = threadIdx.x;
  const float* Wl = W + (size_t)layer * 2048 * 4096;
  char* img = wimg + (size_t)bid * 131072;
  const int kl = tid >> 2, g = tid & 3;                                  // load map
  const int row = tid & 15, ksub = (tid >> 4) & 3;                       // emit map
  const int tn = (tid >> 6) & 1, kl2 = tid >> 7;
  const int c = tn * 16 + row;
#pragma unroll 1
  for (int kt = 0; kt < 32; ++kt) {
    const float* src = Wl + (size_t)(kt * 64 + kl) * 4096 + g * 1024 + u0;
    const float4 v0 = *(const float4*)src;
    const float4 v1 = *(const float4*)(src + 4);
    *(float4*)(tile + kl * 36 + g * 8) = v0;
    *(float4*)(tile + kl * 36 + g * 8 + 4) = v1;
    __syncthreads();
    const int kbase = kl2 * 32 + ksub * 8;
    uint4 u;
    u.x = cvt_pk_bf16(tile[(kbase + 0) * 36 + c], tile[(kbase + 1) * 36 + c]);
    u.y = cvt_pk_bf16(tile[(kbase + 2) * 36 + c], tile[(kbase + 3) * 36 + c]);
    u.z = cvt_pk_bf16(tile[(kbase + 4) * 36 + c], tile[(kbase + 5) * 36 + c]);
    u.w = cvt_pk_bf16(tile[(kbase + 6) * 36 + c], tile[(kbase + 7) * 36 + c]);
    const int S = (kt * 2 + kl2) * 128 + tn * 64 + ksub * 16 + row;
    *(uint4*)(img + (size_t)S * 16) = u;
    __syncthreads();
  }
}

// ---------------- K3: pipelined 2-layer LSTM scan, MFMA gates, W LDS-resident ----------------
// 256 blocks x 512 threads, 1 block/CU. Block: layer=bid>>7, 32 gate-cols at u0=(bid&127)*8.
// Per phase: stage x_cat (bf16) in 16x 8KB chunks (dbuf) -> 8 waves (2tb x 2tn x 2 K-half)
// MFMA 16x16x32 -> 2-way K-reduce via LDS -> cell update (c-state in LDS).
__global__ __launch_bounds__(512, 1) void lstm_seq_kernel(
    const int* __restrict__ tokens, const float* __restrict__ etab,
    const char* __restrict__ wimg, const float* __restrict__ bias,
    const float* __restrict__ c0_in,
    unsigned short* __restrict__ h0buf, unsigned short* __restrict__ h1buf,
    unsigned short* __restrict__ hseq,
    float* __restrict__ out_tail, int* __restrict__ bar)
{
  __shared__ __align__(16) char smem[156672];
  char* wlds   = smem;                        // 131072: W fragment slots
  char* xbuf   = smem + 131072;               // 2 x 8192: x chunk dbuf
  float* red   = (float*)(smem + 147456);     // 4096: K-half partials (4 waves x 64 x f32x4)
  float* gates = (float*)(smem + 151552);     // 4096: [32 b][32 c]
  float* cl    = (float*)(smem + 155648);     // 1024: c-state [32 b][8 u]

  const int tid = threadIdx.x;
  const int bid = blockIdx.x;
  const int layer = bid >> 7;
  const int u0 = (bid & 127) * 8;
  const int lane = tid & 63, w = tid >> 6;
  const int tb = (w >> 1) & 1, tn = w & 1, kh = w >> 2;
  const int b = tid >> 4, kslot = tid & 15;                 // staging map
  const int Sx = (kslot >> 2) * 128 + (b >> 4) * 64 + (kslot & 3) * 16 + (b & 15);
  unsigned short* hmy = layer ? h1buf : h0buf;

  // one-time: W image -> LDS (linear 16B, coalesced), c-state -> LDS
  {
    const char* img = wimg + (size_t)bid * 131072;
#pragma unroll 1
    for (int i = 0; i < 16; ++i) {
      const int off = (i * 512 + tid) * 16;
      __builtin_amdgcn_global_load_lds((gas_ptr)(img + off), (las_ptr)(wlds + off), 16, 0, 0);
    }
    if (tid < 256) cl[tid] = c0_in[layer * 32768 + (tid >> 3) * 1024 + u0 + (tid & 7)];
  }
  const float biasv = bias[layer * 4096 + ((tn * 16 + (lane & 15)) >> 3) * 1024 + u0 +
                           ((tn * 16 + (lane & 15)) & 7)];
  asm volatile("s_waitcnt vmcnt(0)");
  __syncthreads();

  for (int p = 0; p <= 128; ++p) {
    const bool active = layer ? (p >= 1) : (p < 128);
    if (active) {
      const int t = layer ? (p - 1) : p;
      // per-thread x row sources (low K: emb/h0-cur; high K: own h prev), all at slot p&1
      const float* erow = nullptr;
      const unsigned short* xlo = nullptr;
      if (layer == 0) erow = etab + (size_t)tokens[t * 32 + b] * 1024;
      else            xlo = h0buf + (p & 1) * 32768 + b * 1024;
      const unsigned short* xhi = hmy + (p & 1) * 32768 + b * 1024;

      // load one 8-k bf16 fragment of chunk c for this thread
      auto ldfrag = [&](int c) -> uint4 {
        const int k = c * 128 + kslot * 8;
        if (k < 1024) {
          if (layer == 0) {
            const float4 lo = *(const float4*)(erow + k);
            const float4 hi = *(const float4*)(erow + k + 4);
            uint4 r;
            r.x = cvt_pk_bf16(lo.x, lo.y);
            r.y = cvt_pk_bf16(lo.z, lo.w);
            r.z = cvt_pk_bf16(hi.x, hi.y);
            r.w = cvt_pk_bf16(hi.z, hi.w);
            return r;
          }
          return *(const uint4*)(xlo + k);
        }
        return *(const uint4*)(xhi + (k - 1024));
      };

      f32x4 acc = {0.f, 0.f, 0.f, 0.f};
      uint4 st = ldfrag(0);
      *(uint4*)(xbuf + Sx * 16) = st;
      __syncthreads();
#pragma unroll 1
      for (int c = 0; c < 16; ++c) {
        if (c < 15) st = ldfrag(c + 1);
        const char* xb = xbuf + ((c & 1) ? 8192 : 0);
#pragma unroll
        for (int kk = 0; kk < 2; ++kk) {
          const int ks = kh * 2 + kk;
          const bf16x8 af = *(const bf16x8*)(xb + (ks * 128 + tb * 64 + lane) * 16);
          const bf16x8 bf_ = *(const bf16x8*)(wlds + ((size_t)(c * 4 + ks) * 128 + tn * 64 + lane) * 16);
          acc = __builtin_amdgcn_mfma_f32_16x16x32_bf16(af, bf_, acc, 0, 0, 0);
        }
        __syncthreads();
        if (c < 15) {
          *(uint4*)(xbuf + (((c + 1) & 1) ? 8192 : 0) + Sx * 16) = st;
          __syncthreads();
        }
      }
      // 2-way K reduction + bias -> gates
      if (w >= 4) *(f32x4*)(red + ((w - 4) * 64 + lane) * 4) = acc;
      __syncthreads();
      if (w < 4) {
        const f32x4 o = *(const f32x4*)(red + (w * 64 + lane) * 4);
        const int cc = tn * 16 + (lane & 15);
        const int rb = tb * 16 + (lane >> 4) * 4;
#pragma unroll
        for (int r = 0; r < 4; ++r)
          gates[(rb + r) * 32 + cc] = acc[r] + o[r] + biasv;
      }
      __syncthreads();
      // cell update: 256 threads = 32 b x 8 units; c-state stays in LDS
      if (tid < 256) {
        const int cb = tid >> 3, uo = tid & 7, u = u0 + uo;
        const float gi = gates[cb * 32 + uo];
        const float gj = gates[cb * 32 + 8 + uo];
        const float gf = gates[cb * 32 + 16 + uo];
        const float go = gates[cb * 32 + 24 + uo];
        const float cold = cl[tid];
        const float cn = cold * sigm(gf) + sigm(gi) * tanhf(gj);
        const float hn = tanhf(cn) * sigm(go);
        cl[tid] = cn;
        const unsigned short h16 = f2bf(hn);
        hmy[((p + 1) & 1) * 32768 + cb * 1024 + u] = h16;
        if (layer) hseq[(size_t)t * 32768 + cb * 1024 + u] = h16;
        if (t == 127) {
          out_tail[layer * 32768 + cb * 1024 + u] = hn;           // h_last (fp32)
          out_tail[65536 + layer * 32768 + cb * 1024 + u] = cn;   // c_last (fp32)
        }
      }
    }
    if (p < 128) gbar2(bar, p + 1, bid);
  }
}

// ---------------- K4: dec_W [1024][32000] f32 -> Wt [32000][1024] bf16 ----------------
__global__ __launch_bounds__(256) void transpose_decw_kernel(
    const float* __restrict__ decW, unsigned short* __restrict__ Wt)
{
  __shared__ float tile[64 * 68];
  const int bid = blockIdx.x;         // 8000 = 16 k-tiles x 500 n-tiles
  const int k0 = (bid & 15) * 64;
  const int n0 = (bid >> 4) * 64;
  const int tid = threadIdx.x;
  {
    const int kl = tid >> 4, c4 = (tid & 15) * 4;
#pragma unroll
    for (int i = 0; i < 4; ++i) {
      const int kr = kl + 16 * i;
      *(float4*)(tile + kr * 68 + c4) =
          *(const float4*)(decW + (size_t)(k0 + kr) * 32000 + n0 + c4);
    }
  }
  __syncthreads();
  {
    const int nl = tid >> 3, kc = (tid & 7) * 8;
#pragma unroll
    for (int h2 = 0; h2 < 2; ++h2) {
      const int n = nl + 32 * h2;
      float tv[8];
#pragma unroll
      for (int q = 0; q < 8; ++q) tv[q] = tile[(kc + q) * 68 + n];
      uint4 u;
      u.x = cvt_pk_bf16(tv[0], tv[1]);
      u.y = cvt_pk_bf16(tv[2], tv[3]);
      u.z = cvt_pk_bf16(tv[4], tv[5]);
      u.w = cvt_pk_bf16(tv[6], tv[7]);
      *(uint4*)(Wt + (size_t)(n0 + n) * 1024 + k0 + kc) = u;
    }
  }
}

// ---------------- K5: decoder bf16 MFMA GEMM, 128x128 tile, BK=32, double-buffered ----------------
__global__ __launch_bounds__(256) void decoder_kernel(
    const unsigned short* __restrict__ A,   // hseq  [4096][1024] bf16
    const unsigned short* __restrict__ Bt,  // Wt    [32000][1024] bf16 (dec_W^T)
    const float* __restrict__ decb,
    float* __restrict__ out)                // [4096][32000] f32
{
  __shared__ unsigned short Al[2][128 * 32];
  __shared__ unsigned short Bl[2][128 * 32];

  const int bid = blockIdx.x;
  const int swz = (bid & 7) * 1000 + (bid >> 3);  // XCD-contiguous tile chunks (8000 % 8 == 0)
  const int mt = swz / 250, nt = swz % 250;
  const int m0 = mt * 128, n0 = nt * 128;

  const int tid = threadIdx.x;
  const int lane = tid & 63;
  const int wv = tid >> 6;
  const int wr = wv >> 1, wc = wv & 1;
  const int l15 = lane & 15, kg = lane >> 4;

  f32x4 acc[4][4];
#pragma unroll
  for (int mi = 0; mi < 4; ++mi)
#pragma unroll
    for (int ni = 0; ni < 4; ++ni) {
      f32x4 z = {0.f, 0.f, 0.f, 0.f};
      acc[mi][ni] = z;
    }

  auto stage = [&](const unsigned short* src, int row0, int k0, unsigned short* lds) {
#pragma unroll
    for (int j = 0; j < 2; ++j) {
      const int chunk = (wv * 2 + j) * 64 + lane;   // 512 x 16B per tile
      const int r = chunk >> 2, kc = chunk & 3;
      const unsigned short* g = src + (size_t)(row0 + r) * 1024 + k0 + kc * 8;
      __builtin_amdgcn_global_load_lds((gas_ptr)g, (las_ptr)(lds + chunk * 8), 16, 0, 0);
    }
  };

  stage(A, m0, 0, Al[0]);
  stage(Bt, n0, 0, Bl[0]);
  __syncthreads();

  int buf = 0;
  for (int kt = 0; kt < 32; ++kt) {
    if (kt < 31) {
      stage(A, m0, (kt + 1) * 32, Al[buf ^ 1]);
      stage(Bt, n0, (kt + 1) * 32, Bl[buf ^ 1]);
    }
    bf16x8 a[4], b[4];
#pragma unroll
    for (int mi = 0; mi < 4; ++mi)
      a[mi] = *(const bf16x8*)&Al[buf][(wr * 64 + mi * 16 + l15) * 32 + kg * 8];
#pragma unroll
    for (int ni = 0; ni < 4; ++ni)
      b[ni] = *(const bf16x8*)&Bl[buf][(wc * 64 + ni * 16 + l15) * 32 + kg * 8];
#pragma unroll
    for (int mi = 0; mi < 4; ++mi)
#pragma unroll
      for (int ni = 0; ni < 4; ++ni)
        acc[mi][ni] = __builtin_amdgcn_mfma_f32_16x16x32_bf16(a[mi], b[ni], acc[mi][ni], 0, 0, 0);
    __syncthreads();  // drains vmcnt (stage kt+1 done) + protects buf reuse
    buf ^= 1;
  }

#pragma unroll
  for (int ni = 0; ni < 4; ++ni) {
    const int ocol = n0 + wc * 64 + ni * 16 + l15;   // C/D: col = lane&15
    const float bv = decb[ocol];
#pragma unroll
    for (int mi = 0; mi < 4; ++mi) {
      const int orow = m0 + wr * 64 + mi * 16 + kg * 4;  // row = (lane>>4)*4 + reg
#pragma unroll
      for (int r = 0; r < 4; ++r)
        out[(size_t)(orow + r) * 32000 + ocol] = acc[mi][ni][r] + bv;
    }
  }
}

extern "C" void kernel_launch(void* const* d_in, const int* in_sizes, int n_in,
                              void* d_out, int out_size, void* d_ws, size_t ws_size,
                              hipStream_t stream) {
  (void)in_sizes; (void)n_in; (void)out_size; (void)ws_size;
  const int* tokens  = (const int*)d_in[0];
  const float* h0_in = (const float*)d_in[1];
  const float* c0_in = (const float*)d_in[2];
  const float* etab  = (const float*)d_in[3];
  const float* lstmW = (const float*)d_in[4];
  const float* lstmb = (const float*)d_in[5];
  const float* decW  = (const float*)d_in[6];
  const float* decb  = (const float*)d_in[7];
  float* out = (float*)d_out;

  char* ws = (char*)d_ws;
  unsigned short* hseq  = (unsigned short*)(ws + 0);         //  8,388,608 B
  char* img             = ws + 8388608;                      // 33,554,432 B (lstm phase)
  unsigned short* Wt    = (unsigned short*)(ws + 8388608);   // 65,536,000 B (decoder phase, overlaps img)
  unsigned short* h0buf = (unsigned short*)(ws + 73924608);  //    131,072 B (bf16, 2 slots)
  unsigned short* h1buf = (unsigned short*)(ws + 74055680);  //    131,072 B
  int* bar              = (int*)(ws + 74186752);             //      3,072 B

  init_kernel<<<128, 256, 0, stream>>>(h0_in, h0buf, h1buf, bar);
  reorg_lstm_w<<<256, 256, 0, stream>>>(lstmW, img);
  lstm_seq_kernel<<<256, 512, 0, stream>>>(tokens, etab, img, lstmb, c0_in,
                                           h0buf, h1buf, hseq,
                                           out + 131072000, bar);
  transpose_decw_kernel<<<8000, 256, 0, stream>>>(decW, Wt);
  decoder_kernel<<<8000, 256, 0, stream>>>(hseq, Wt, decb, out);
}

// Round 5
// 3727.996 us; speedup vs baseline: 10.7282x; 1.0188x over previous
//
#include <hip/hip_runtime.h>

typedef __attribute__((ext_vector_type(8))) short bf16x8;
typedef __attribute__((ext_vector_type(4))) float f32x4;
typedef const __attribute__((address_space(1))) void* gas_ptr;
typedef __attribute__((address_space(3))) void* las_ptr;

__device__ __forceinline__ unsigned short f2bf(float f) {
  unsigned int u = __float_as_uint(f);
  return (unsigned short)((u + 0x7fffu + ((u >> 16) & 1u)) >> 16);  // RNE
}
__device__ __forceinline__ unsigned int cvt_pk_bf16(float a, float b) {
  unsigned int r;
  asm volatile("v_cvt_pk_bf16_f32 %0, %1, %2" : "=v"(r) : "v"(a), "v"(b));
  return r;
}
__device__ __forceinline__ float sigm(float x) { return 1.0f / (1.0f + __expf(-x)); }

// ---- two-level grid barrier; mostly-RELAXED polling (acquire every 8th poll) ----
__device__ __forceinline__ void gbar2(int* bars, int target, int bid) {
  __syncthreads();
  if (threadIdx.x == 0) {
    __threadfence();  // release: h stores -> IF before signaling
    int* leaf  = bars + (bid & 15) * 32;
    int* mcnt  = bars + 512;
    int* sense = bars + 640;
    if (__hip_atomic_fetch_add(leaf, 1, __ATOMIC_ACQ_REL, __HIP_MEMORY_SCOPE_AGENT) == 15) {
      __hip_atomic_store(leaf, 0, __ATOMIC_RELAXED, __HIP_MEMORY_SCOPE_AGENT);
      if (__hip_atomic_fetch_add(mcnt, 1, __ATOMIC_ACQ_REL, __HIP_MEMORY_SCOPE_AGENT) == 15) {
        __hip_atomic_store(mcnt, 0, __ATOMIC_RELAXED, __HIP_MEMORY_SCOPE_AGENT);
        __hip_atomic_store(sense, target, __ATOMIC_RELEASE, __HIP_MEMORY_SCOPE_AGENT);
      }
    }
    int v = __hip_atomic_load(sense, __ATOMIC_RELAXED, __HIP_MEMORY_SCOPE_AGENT);
    int it = 0;
    while (v < target) {
      __builtin_amdgcn_s_sleep(2);
      ++it;
      v = ((it & 7) == 0)
            ? __hip_atomic_load(sense, __ATOMIC_ACQUIRE, __HIP_MEMORY_SCOPE_AGENT)
            : __hip_atomic_load(sense, __ATOMIC_RELAXED, __HIP_MEMORY_SCOPE_AGENT);
    }
    __threadfence();  // acquire: invalidate L1/L2 once before data reads
  }
  __syncthreads();
}

// ---------------- K1: h0 -> bf16 double-buffered state, zero barrier ----------------
__global__ __launch_bounds__(256) void init_kernel(
    const float* __restrict__ h0_in,
    unsigned short* __restrict__ h0buf, unsigned short* __restrict__ h1buf,
    int* __restrict__ bar)
{
  const int j = blockIdx.x * 256 + threadIdx.x;   // 0..32767
  if (j < 768) bar[j] = 0;
  h0buf[j] = f2bf(h0_in[j]);                 // layer0 h -> h0buf slot0
  h1buf[32768 + j] = f2bf(h0_in[32768 + j]); // layer1 h -> h1buf slot1
}

// ---------------- K1b: gather emb[tokens] -> xemb bf16 [128*32][1024] ----------------
__global__ __launch_bounds__(256) void gather_emb(
    const int* __restrict__ tokens, const float* __restrict__ etab,
    unsigned short* __restrict__ xemb)
{
  const int r = blockIdx.x;                       // t*32 + b
  const float* src = etab + (size_t)tokens[r] * 1024;
  const int q = threadIdx.x * 4;
  const float4 v = *(const float4*)(src + q);
  uint2 o;
  o.x = cvt_pk_bf16(v.x, v.y);
  o.y = cvt_pk_bf16(v.z, v.w);
  *(uint2*)(xemb + (size_t)r * 1024 + q) = o;
}

// ---------------- K2: lstm_W -> per-block MFMA-fragment-slot images (bf16) ----------------
// Image for lstm block bid (layer=bid>>7, u0=(bid&127)*8): 8192 slots x 16B, slot
// S = kt*128 + tn*64 + lane ; content = W[kt*32 + (lane>>4)*8 .. +8][gcol] as 8 bf16,
// where c = tn*16 + (lane&15), gcol = (c>>3)*1024 + u0 + (c&7).
__global__ __launch_bounds__(256) void reorg_lstm_w(
    const float* __restrict__ W, char* __restrict__ wimg)
{
  __shared__ float tile[64 * 36];
  const int bid = blockIdx.x;            // 256 = lstm block id
  const int layer = bid >> 7;
  const int u0 = (bid & 127) * 8;
  const int tid = threadIdx.x;
  const float* Wl = W + (size_t)layer * 2048 * 4096;
  char* img = wimg + (size_t)bid * 131072;
  const int kl = tid >> 2, g = tid & 3;                                  // load map
  const int row = tid & 15, ksub = (tid >> 4) & 3;                       // emit map
  const int tn = (tid >> 6) & 1, kl2 = tid >> 7;
  const int c = tn * 16 + row;
#pragma unroll 1
  for (int kt = 0; kt < 32; ++kt) {
    const float* src = Wl + (size_t)(kt * 64 + kl) * 4096 + g * 1024 + u0;
    const float4 v0 = *(const float4*)src;
    const float4 v1 = *(const float4*)(src + 4);
    *(float4*)(tile + kl * 36 + g * 8) = v0;
    *(float4*)(tile + kl * 36 + g * 8 + 4) = v1;
    __syncthreads();
    const int kbase = kl2 * 32 + ksub * 8;
    uint4 u;
    u.x = cvt_pk_bf16(tile[(kbase + 0) * 36 + c], tile[(kbase + 1) * 36 + c]);
    u.y = cvt_pk_bf16(tile[(kbase + 2) * 36 + c], tile[(kbase + 3) * 36 + c]);
    u.z = cvt_pk_bf16(tile[(kbase + 4) * 36 + c], tile[(kbase + 5) * 36 + c]);
    u.w = cvt_pk_bf16(tile[(kbase + 6) * 36 + c], tile[(kbase + 7) * 36 + c]);
    const int S = (kt * 2 + kl2) * 128 + tn * 64 + ksub * 16 + row;
    *(uint4*)(img + (size_t)S * 16) = u;
    __syncthreads();
  }
}

// ---------------- K3: pipelined 2-layer LSTM scan; A-frags direct global->VGPR ----------------
// 256 blocks x 512 threads, 1/CU. Block: layer=bid>>7, 32 gate-cols at u0=(bid&127)*8.
// Wave w: tb=(w>>1)&1 (16 batch rows), tn=w&1 (16 cols), kh=w>>2 (1024-K half).
// 32 MFMA/wave/phase; A loaded straight from global (16B/lane), W from LDS (lane-linear).
__global__ __launch_bounds__(512, 1) void lstm_seq_kernel(
    const char* __restrict__ wimg, const float* __restrict__ bias,
    const float* __restrict__ c0_in,
    const unsigned short* __restrict__ xemb,
    unsigned short* __restrict__ h0buf, unsigned short* __restrict__ h1buf,
    unsigned short* __restrict__ hseq,
    float* __restrict__ out_tail, int* __restrict__ bar)
{
  __shared__ __align__(16) char smem[140416];
  char* wlds   = smem;                        // 131072: W fragment slots
  float* red   = (float*)(smem + 131072);     //   4096: kh=1 partials (4 waves x 64 x f32x4)
  float* gates = (float*)(smem + 135168);     //   4224: [32 b][33] padded
  float* cl    = (float*)(smem + 139392);     //   1024: c-state [32 b][8 u]

  const int tid = threadIdx.x;
  const int bid = blockIdx.x;
  const int layer = bid >> 7;
  const int u0 = (bid & 127) * 8;
  const int lane = tid & 63, w = tid >> 6;
  const int tb = (w >> 1) & 1, tn = w & 1, kh = w >> 2;
  const int row = tb * 16 + (lane & 15);
  const int kg = lane >> 4;
  unsigned short* hmy = layer ? h1buf : h0buf;

  // one-time: W image -> LDS (linear 16B, coalesced), c-state -> LDS
  {
    const char* img = wimg + (size_t)bid * 131072;
#pragma unroll 1
    for (int i = 0; i < 16; ++i) {
      const int off = (i * 512 + tid) * 16;
      __builtin_amdgcn_global_load_lds((gas_ptr)(img + off), (las_ptr)(wlds + off), 16, 0, 0);
    }
    if (tid < 256) cl[tid] = c0_in[layer * 32768 + (tid >> 3) * 1024 + u0 + (tid & 7)];
  }
  const int cc = tn * 16 + (lane & 15);
  const float biasv = bias[layer * 4096 + (cc >> 3) * 1024 + u0 + (cc & 7)];
  asm volatile("s_waitcnt vmcnt(0)");
  __syncthreads();

  const char* wbase = wlds + (size_t)(kh * 4096 + tn * 64 + lane) * 16;

  for (int p = 0; p <= 128; ++p) {
    const bool active = layer ? (p >= 1) : (p < 128);
    if (active) {
      const int t = layer ? (p - 1) : p;
      const char* xlo_base = (layer == 0)
          ? (const char*)(xemb + (size_t)t * 32768)
          : (const char*)(h0buf + (p & 1) * 32768);
      const char* xhi_base = (const char*)(hmy + (p & 1) * 32768);
      const char* xb = (kh ? xhi_base : xlo_base) + row * 2048 + kg * 16;

      f32x4 acc0 = {0.f, 0.f, 0.f, 0.f}, acc1 = {0.f, 0.f, 0.f, 0.f};
      bf16x8 a0[8], a1[8];
      auto mm8 = [&](const bf16x8* A, int ko) {
#pragma unroll
        for (int j = 0; j < 8; ++j) {
          const bf16x8 bw = *(const bf16x8*)(wbase + (size_t)(ko + j) * 2048);
          if (j & 1) acc1 = __builtin_amdgcn_mfma_f32_16x16x32_bf16(A[j], bw, acc1, 0, 0, 0);
          else       acc0 = __builtin_amdgcn_mfma_f32_16x16x32_bf16(A[j], bw, acc0, 0, 0, 0);
        }
      };
#pragma unroll
      for (int j = 0; j < 8; ++j) a0[j] = *(const bf16x8*)(xb + j * 64);
#pragma unroll
      for (int j = 0; j < 8; ++j) a1[j] = *(const bf16x8*)(xb + 512 + j * 64);
      mm8(a0, 0);
#pragma unroll
      for (int j = 0; j < 8; ++j) a0[j] = *(const bf16x8*)(xb + 1024 + j * 64);
      mm8(a1, 8);
#pragma unroll
      for (int j = 0; j < 8; ++j) a1[j] = *(const bf16x8*)(xb + 1536 + j * 64);
      mm8(a0, 16);
      mm8(a1, 24);

      f32x4 acc;
#pragma unroll
      for (int r = 0; r < 4; ++r) acc[r] = acc0[r] + acc1[r];

      // 2-way K reduction (kh=1 -> LDS, kh=0 sums) + bias -> gates
      if (kh) *(f32x4*)(red + ((w - 4) * 64 + lane) * 4) = acc;
      __syncthreads();
      if (!kh) {
        const f32x4 o = *(const f32x4*)(red + (w * 64 + lane) * 4);
        const int rb = tb * 16 + kg * 4;
#pragma unroll
        for (int r = 0; r < 4; ++r)
          gates[(rb + r) * 33 + cc] = acc[r] + o[r] + biasv;
      }
      __syncthreads();
      // cell update: 256 threads = 32 b x 8 units; c-state stays in LDS
      if (tid < 256) {
        const int cb = tid >> 3, uo = tid & 7, u = u0 + uo;
        const float gi = gates[cb * 33 + uo];
        const float gj = gates[cb * 33 + 8 + uo];
        const float gf = gates[cb * 33 + 16 + uo];
        const float go = gates[cb * 33 + 24 + uo];
        const float cold = cl[tid];
        const float cn = cold * sigm(gf) + sigm(gi) * tanhf(gj);
        const float hn = tanhf(cn) * sigm(go);
        cl[tid] = cn;
        const unsigned short h16 = f2bf(hn);
        hmy[((p + 1) & 1) * 32768 + cb * 1024 + u] = h16;
        if (layer) hseq[(size_t)t * 32768 + cb * 1024 + u] = h16;
        if (t == 127) {
          out_tail[layer * 32768 + cb * 1024 + u] = hn;           // h_last (fp32)
          out_tail[65536 + layer * 32768 + cb * 1024 + u] = cn;   // c_last (fp32)
        }
      }
    }
    if (p < 128) gbar2(bar, p + 1, bid);
  }
}

// ---------------- K4: dec_W [1024][32000] f32 -> Wt [32000][1024] bf16 ----------------
__global__ __launch_bounds__(256) void transpose_decw_kernel(
    const float* __restrict__ decW, unsigned short* __restrict__ Wt)
{
  __shared__ float tile[64 * 68];
  const int bid = blockIdx.x;         // 8000 = 16 k-tiles x 500 n-tiles
  const int k0 = (bid & 15) * 64;
  const int n0 = (bid >> 4) * 64;
  const int tid = threadIdx.x;
  {
    const int kl = tid >> 4, c4 = (tid & 15) * 4;
#pragma unroll
    for (int i = 0; i < 4; ++i) {
      const int kr = kl + 16 * i;
      *(float4*)(tile + kr * 68 + c4) =
          *(const float4*)(decW + (size_t)(k0 + kr) * 32000 + n0 + c4);
    }
  }
  __syncthreads();
  {
    const int nl = tid >> 3, kc = (tid & 7) * 8;
#pragma unroll
    for (int h2 = 0; h2 < 2; ++h2) {
      const int n = nl + 32 * h2;
      float tv[8];
#pragma unroll
      for (int q = 0; q < 8; ++q) tv[q] = tile[(kc + q) * 68 + n];
      uint4 u;
      u.x = cvt_pk_bf16(tv[0], tv[1]);
      u.y = cvt_pk_bf16(tv[2], tv[3]);
      u.z = cvt_pk_bf16(tv[4], tv[5]);
      u.w = cvt_pk_bf16(tv[6], tv[7]);
      *(uint4*)(Wt + (size_t)(n0 + n) * 1024 + k0 + kc) = u;
    }
  }
}

// ---------------- K5: decoder bf16 MFMA GEMM, 128x128 tile, BK=32, double-buffered ----------------
__global__ __launch_bounds__(256) void decoder_kernel(
    const unsigned short* __restrict__ A,   // hseq  [4096][1024] bf16
    const unsigned short* __restrict__ Bt,  // Wt    [32000][1024] bf16 (dec_W^T)
    const float* __restrict__ decb,
    float* __restrict__ out)                // [4096][32000] f32
{
  __shared__ unsigned short Al[2][128 * 32];
  __shared__ unsigned short Bl[2][128 * 32];

  const int bid = blockIdx.x;
  const int swz = (bid & 7) * 1000 + (bid >> 3);  // XCD-contiguous tile chunks (8000 % 8 == 0)
  const int mt = swz / 250, nt = swz % 250;
  const int m0 = mt * 128, n0 = nt * 128;

  const int tid = threadIdx.x;
  const int lane = tid & 63;
  const int wv = tid >> 6;
  const int wr = wv >> 1, wc = wv & 1;
  const int l15 = lane & 15, kg = lane >> 4;

  f32x4 acc[4][4];
#pragma unroll
  for (int mi = 0; mi < 4; ++mi)
#pragma unroll
    for (int ni = 0; ni < 4; ++ni) {
      f32x4 z = {0.f, 0.f, 0.f, 0.f};
      acc[mi][ni] = z;
    }

  auto stage = [&](const unsigned short* src, int row0, int k0, unsigned short* lds) {
#pragma unroll
    for (int j = 0; j < 2; ++j) {
      const int chunk = (wv * 2 + j) * 64 + lane;   // 512 x 16B per tile
      const int r = chunk >> 2, kc = chunk & 3;
      const unsigned short* g = src + (size_t)(row0 + r) * 1024 + k0 + kc * 8;
      __builtin_amdgcn_global_load_lds((gas_ptr)g, (las_ptr)(lds + chunk * 8), 16, 0, 0);
    }
  };

  stage(A, m0, 0, Al[0]);
  stage(Bt, n0, 0, Bl[0]);
  __syncthreads();

  int buf = 0;
  for (int kt = 0; kt < 32; ++kt) {
    if (kt < 31) {
      stage(A, m0, (kt + 1) * 32, Al[buf ^ 1]);
      stage(Bt, n0, (kt + 1) * 32, Bl[buf ^ 1]);
    }
    bf16x8 a[4], b[4];
#pragma unroll
    for (int mi = 0; mi < 4; ++mi)
      a[mi] = *(const bf16x8*)&Al[buf][(wr * 64 + mi * 16 + l15) * 32 + kg * 8];
#pragma unroll
    for (int ni = 0; ni < 4; ++ni)
      b[ni] = *(const bf16x8*)&Bl[buf][(wc * 64 + ni * 16 + l15) * 32 + kg * 8];
#pragma unroll
    for (int mi = 0; mi < 4; ++mi)
#pragma unroll
      for (int ni = 0; ni < 4; ++ni)
        acc[mi][ni] = __builtin_amdgcn_mfma_f32_16x16x32_bf16(a[mi], b[ni], acc[mi][ni], 0, 0, 0);
    __syncthreads();  // drains vmcnt (stage kt+1 done) + protects buf reuse
    buf ^= 1;
  }

#pragma unroll
  for (int ni = 0; ni < 4; ++ni) {
    const int ocol = n0 + wc * 64 + ni * 16 + l15;   // C/D: col = lane&15
    const float bv = decb[ocol];
#pragma unroll
    for (int mi = 0; mi < 4; ++mi) {
      const int orow = m0 + wr * 64 + mi * 16 + kg * 4;  // row = (lane>>4)*4 + reg
#pragma unroll
      for (int r = 0; r < 4; ++r)
        out[(size_t)(orow + r) * 32000 + ocol] = acc[mi][ni][r] + bv;
    }
  }
}

extern "C" void kernel_launch(void* const* d_in, const int* in_sizes, int n_in,
                              void* d_out, int out_size, void* d_ws, size_t ws_size,
                              hipStream_t stream) {
  (void)in_sizes; (void)n_in; (void)out_size; (void)ws_size;
  const int* tokens  = (const int*)d_in[0];
  const float* h0_in = (const float*)d_in[1];
  const float* c0_in = (const float*)d_in[2];
  const float* etab  = (const float*)d_in[3];
  const float* lstmW = (const float*)d_in[4];
  const float* lstmb = (const float*)d_in[5];
  const float* decW  = (const float*)d_in[6];
  const float* decb  = (const float*)d_in[7];
  float* out = (float*)d_out;

  char* ws = (char*)d_ws;
  unsigned short* hseq  = (unsigned short*)(ws + 0);         //  8,388,608 B
  char* img             = ws + 8388608;                      // 33,554,432 B (lstm phase)
  unsigned short* Wt    = (unsigned short*)(ws + 8388608);   // 65,536,000 B (decoder phase, overlaps img+xemb)
  unsigned short* xemb  = (unsigned short*)(ws + 41943040);  //  8,388,608 B (lstm phase)
  unsigned short* h0buf = (unsigned short*)(ws + 73924608);  //    131,072 B (bf16, 2 slots)
  unsigned short* h1buf = (unsigned short*)(ws + 74055680);  //    131,072 B
  int* bar              = (int*)(ws + 74186752);             //      3,072 B

  init_kernel<<<128, 256, 0, stream>>>(h0_in, h0buf, h1buf, bar);
  gather_emb<<<4096, 256, 0, stream>>>(tokens, etab, xemb);
  reorg_lstm_w<<<256, 256, 0, stream>>>(lstmW, img);
  lstm_seq_kernel<<<256, 512, 0, stream>>>(img, lstmb, c0_in, xemb,
                                           h0buf, h1buf, hseq,
                                           out + 131072000, bar);
  transpose_decw_kernel<<<8000, 256, 0, stream>>>(decW, Wt);
  decoder_kernel<<<8000, 256, 0, stream>>>(hseq, Wt, decb, out);
}

// Round 6
// 2667.906 us; speedup vs baseline: 14.9910x; 1.3973x over previous
//
#include <hip/hip_runtime.h>

typedef __attribute__((ext_vector_type(8))) short bf16x8;
typedef __attribute__((ext_vector_type(4))) float f32x4;
typedef const __attribute__((address_space(1))) void* gas_ptr;
typedef __attribute__((address_space(3))) void* las_ptr;

__device__ __forceinline__ unsigned short f2bf(float f) {
  unsigned int u = __float_as_uint(f);
  return (unsigned short)((u + 0x7fffu + ((u >> 16) & 1u)) >> 16);  // RNE
}
__device__ __forceinline__ unsigned int cvt_pk_bf16(float a, float b) {
  unsigned int r;
  asm volatile("v_cvt_pk_bf16_f32 %0, %1, %2" : "=v"(r) : "v"(a), "v"(b));
  return r;
}
__device__ __forceinline__ float sigm(float x) { return 1.0f / (1.0f + __expf(-x)); }

// device-coherent (sc0 sc1) helpers: relaxed agent atomics bypass L1/L2, served at IF.
__device__ __forceinline__ unsigned int ld_cv(const unsigned int* p) {
  return __hip_atomic_load(p, __ATOMIC_RELAXED, __HIP_MEMORY_SCOPE_AGENT);
}
__device__ __forceinline__ void st_cv(unsigned int* p, unsigned int v) {
  __hip_atomic_store(p, v, __ATOMIC_RELAXED, __HIP_MEMORY_SCOPE_AGENT);
}

// ---- fence-free two-level grid barrier (16 leaves x 16 blocks + master) ----
// No __threadfence: h hand-off data uses sc0sc1 atomics (write-through/bypass), and
// __syncthreads before the signal drains all waves' stores (vmcnt(0) precedes s_barrier).
__device__ __forceinline__ void gbarF(int* bars, int target, int bid) {
  __syncthreads();
  if (threadIdx.x == 0) {
    int* leaf  = bars + (bid & 15) * 32;
    int* mcnt  = bars + 512;
    int* sense = bars + 640;
    if (__hip_atomic_fetch_add(leaf, 1, __ATOMIC_RELAXED, __HIP_MEMORY_SCOPE_AGENT) == 15) {
      __hip_atomic_store(leaf, 0, __ATOMIC_RELAXED, __HIP_MEMORY_SCOPE_AGENT);
      if (__hip_atomic_fetch_add(mcnt, 1, __ATOMIC_RELAXED, __HIP_MEMORY_SCOPE_AGENT) == 15) {
        __hip_atomic_store(mcnt, 0, __ATOMIC_RELAXED, __HIP_MEMORY_SCOPE_AGENT);
        __hip_atomic_store(sense, target, __ATOMIC_RELAXED, __HIP_MEMORY_SCOPE_AGENT);
      }
    }
    while (__hip_atomic_load(sense, __ATOMIC_RELAXED, __HIP_MEMORY_SCOPE_AGENT) < target)
      __builtin_amdgcn_s_sleep(1);
  }
  __syncthreads();
}

// ---------------- K1: h0 -> bf16 double-buffered state, zero barrier ----------------
__global__ __launch_bounds__(256) void init_kernel(
    const float* __restrict__ h0_in,
    unsigned short* __restrict__ h0buf, unsigned short* __restrict__ h1buf,
    int* __restrict__ bar)
{
  const int j = blockIdx.x * 256 + threadIdx.x;   // 0..32767
  if (j < 768) bar[j] = 0;
  h0buf[j] = f2bf(h0_in[j]);                 // layer0 h -> h0buf slot0
  h1buf[32768 + j] = f2bf(h0_in[32768 + j]); // layer1 h -> h1buf slot1
}

// ---------------- K1b: gather emb[tokens] -> xemb bf16 [128*32][1024] ----------------
__global__ __launch_bounds__(256) void gather_emb(
    const int* __restrict__ tokens, const float* __restrict__ etab,
    unsigned short* __restrict__ xemb)
{
  const int r = blockIdx.x;                       // t*32 + b
  const float* src = etab + (size_t)tokens[r] * 1024;
  const int q = threadIdx.x * 4;
  const float4 v = *(const float4*)(src + q);
  uint2 o;
  o.x = cvt_pk_bf16(v.x, v.y);
  o.y = cvt_pk_bf16(v.z, v.w);
  *(uint2*)(xemb + (size_t)r * 1024 + q) = o;
}

// ---------------- K2: lstm_W -> per-block MFMA-fragment-slot images (bf16) ----------------
// Image for lstm block bid (layer=bid>>7, u0=(bid&127)*8): 8192 slots x 16B, slot
// S = kt*128 + tn*64 + lane ; content = W[kt*32 + (lane>>4)*8 .. +8][gcol] as 8 bf16,
// where c = tn*16 + (lane&15), gcol = (c>>3)*1024 + u0 + (c&7).
__global__ __launch_bounds__(256) void reorg_lstm_w(
    const float* __restrict__ W, char* __restrict__ wimg)
{
  __shared__ float tile[64 * 36];
  const int bid = blockIdx.x;            // 256 = lstm block id
  const int layer = bid >> 7;
  const int u0 = (bid & 127) * 8;
  const int tid = threadIdx.x;
  const float* Wl = W + (size_t)layer * 2048 * 4096;
  char* img = wimg + (size_t)bid * 131072;
  const int kl = tid >> 2, g = tid & 3;                                  // load map
  const int row = tid & 15, ksub = (tid >> 4) & 3;                       // emit map
  const int tn = (tid >> 6) & 1, kl2 = tid >> 7;
  const int c = tn * 16 + row;
#pragma unroll 1
  for (int kt = 0; kt < 32; ++kt) {
    const float* src = Wl + (size_t)(kt * 64 + kl) * 4096 + g * 1024 + u0;
    const float4 v0 = *(const float4*)src;
    const float4 v1 = *(const float4*)(src + 4);
    *(float4*)(tile + kl * 36 + g * 8) = v0;
    *(float4*)(tile + kl * 36 + g * 8 + 4) = v1;
    __syncthreads();
    const int kbase = kl2 * 32 + ksub * 8;
    uint4 u;
    u.x = cvt_pk_bf16(tile[(kbase + 0) * 36 + c], tile[(kbase + 1) * 36 + c]);
    u.y = cvt_pk_bf16(tile[(kbase + 2) * 36 + c], tile[(kbase + 3) * 36 + c]);
    u.z = cvt_pk_bf16(tile[(kbase + 4) * 36 + c], tile[(kbase + 5) * 36 + c]);
    u.w = cvt_pk_bf16(tile[(kbase + 6) * 36 + c], tile[(kbase + 7) * 36 + c]);
    const int S = (kt * 2 + kl2) * 128 + tn * 64 + ksub * 16 + row;
    *(uint4*)(img + (size_t)S * 16) = u;
    __syncthreads();
  }
}

// ---------------- K3: pipelined 2-layer LSTM scan; fence-free sc0sc1 h hand-off ----------------
// 256 blocks x 512 threads, 1/CU. Block: layer=bid>>7, 32 gate-cols at u0=(bid&127)*8.
// Wave w: tb=w&1 (16 batch rows), kq=w>>1 (512-K quarter). Each wave: 16 A-frags (read once),
// 32 MFMAs (both tn halves share A in-register). 4-way K reduce via LDS, c-state in LDS.
__global__ __launch_bounds__(512, 1) void lstm_seq_kernel(
    const char* __restrict__ wimg, const float* __restrict__ bias,
    const float* __restrict__ c0_in,
    const unsigned short* __restrict__ xemb,
    unsigned short* __restrict__ h0buf, unsigned short* __restrict__ h1buf,
    unsigned short* __restrict__ hseq,
    float* __restrict__ out_tail, int* __restrict__ bar)
{
  __shared__ __align__(16) char smem[148608];
  char* wlds   = smem;                        // 131072: W fragment slots
  float* red   = (float*)(smem + 131072);     //  12288: K-quarter partials (12 x 64 x f32x4)
  float* gates = (float*)(smem + 143360);     //   4224: [32 b][33] padded
  float* cl    = (float*)(smem + 147584);     //   1024: c-state [32 b][8 u]

  const int tid = threadIdx.x;
  const int bid = blockIdx.x;
  const int layer = bid >> 7;
  const int u0 = (bid & 127) * 8;
  const int lane = tid & 63, w = tid >> 6;
  const int tb = w & 1, kq = w >> 1;
  const int row = tb * 16 + (lane & 15);
  const int kg = lane >> 4;
  unsigned short* hmy = layer ? h1buf : h0buf;

  // one-time: W image -> LDS (linear 16B, coalesced), c-state -> LDS
  {
    const char* img = wimg + (size_t)bid * 131072;
#pragma unroll 1
    for (int i = 0; i < 16; ++i) {
      const int off = (i * 512 + tid) * 16;
      __builtin_amdgcn_global_load_lds((gas_ptr)(img + off), (las_ptr)(wlds + off), 16, 0, 0);
    }
    if (tid < 256) cl[tid] = c0_in[layer * 32768 + (tid >> 3) * 1024 + u0 + (tid & 7)];
  }
  const int cc = lane & 15;
  const float biasv0 = bias[layer * 4096 + (cc >> 3) * 1024 + u0 + (cc & 7)];         // tn=0 col
  const float biasv1 = bias[layer * 4096 + ((cc + 16) >> 3) * 1024 + u0 + (cc & 7)];  // tn=1 col
  asm volatile("s_waitcnt vmcnt(0)");
  __syncthreads();

  const char* wq = wlds + (size_t)(kq * 16 * 128 + lane) * 16;

  for (int p = 0; p <= 128; ++p) {
    const bool active = layer ? (p >= 1) : (p < 128);
    if (active) {
      const int t = layer ? (p - 1) : p;
      // this wave's x source: kq<2 -> low-K input (emb for L0 cached, h0 cur for L1 coherent);
      // kq>=2 -> own h(prev), coherent. Byte base for frag j: xb + j*64.
      const char* xb;
      bool coh;
      if (kq < 2) {
        if (layer == 0) {
          xb = (const char*)xemb + (size_t)t * 65536 + row * 2048 + (kq & 1) * 1024 + kg * 16;
          coh = false;
        } else {
          xb = (const char*)h0buf + (p & 1) * 65536 + row * 2048 + (kq & 1) * 1024 + kg * 16;
          coh = true;
        }
      } else {
        xb = (const char*)hmy + (p & 1) * 65536 + row * 2048 + (kq & 1) * 1024 + kg * 16;
        coh = true;
      }

      bf16x8 a[16];
      if (!coh) {
#pragma unroll
        for (int j = 0; j < 16; ++j) a[j] = *(const bf16x8*)(xb + j * 64);
      } else {
#pragma unroll
        for (int j = 0; j < 16; ++j) {
          const unsigned int* sp = (const unsigned int*)(xb + j * 64);
          union { unsigned int u[4]; bf16x8 v; } cvu;
          cvu.u[0] = ld_cv(sp + 0);
          cvu.u[1] = ld_cv(sp + 1);
          cvu.u[2] = ld_cv(sp + 2);
          cvu.u[3] = ld_cv(sp + 3);
          a[j] = cvu.v;
        }
      }

      f32x4 acc0 = {0.f, 0.f, 0.f, 0.f}, acc1 = {0.f, 0.f, 0.f, 0.f};
#pragma unroll
      for (int j = 0; j < 16; ++j) {
        const bf16x8 b0 = *(const bf16x8*)(wq + (size_t)j * 2048);
        const bf16x8 b1 = *(const bf16x8*)(wq + (size_t)j * 2048 + 1024);
        acc0 = __builtin_amdgcn_mfma_f32_16x16x32_bf16(a[j], b0, acc0, 0, 0, 0);
        acc1 = __builtin_amdgcn_mfma_f32_16x16x32_bf16(a[j], b1, acc1, 0, 0, 0);
      }

      // 4-way K-quarter reduction: kq>0 waves dump, kq==0 waves sum + bias -> gates
      if (kq > 0) {
        const int s0 = (((kq - 1) * 2 + tb) * 2 + 0) * 64 + lane;
        const int s1 = (((kq - 1) * 2 + tb) * 2 + 1) * 64 + lane;
        *(f32x4*)(red + s0 * 4) = acc0;
        *(f32x4*)(red + s1 * 4) = acc1;
      }
      __syncthreads();
      if (kq == 0) {
#pragma unroll
        for (int q = 1; q < 4; ++q) {
          const f32x4 o0 = *(const f32x4*)(red + ((((q - 1) * 2 + tb) * 2 + 0) * 64 + lane) * 4);
          const f32x4 o1 = *(const f32x4*)(red + ((((q - 1) * 2 + tb) * 2 + 1) * 64 + lane) * 4);
#pragma unroll
          for (int r = 0; r < 4; ++r) { acc0[r] += o0[r]; acc1[r] += o1[r]; }
        }
        const int rb = tb * 16 + kg * 4;
#pragma unroll
        for (int r = 0; r < 4; ++r) {
          gates[(rb + r) * 33 + cc] = acc0[r] + biasv0;
          gates[(rb + r) * 33 + 16 + cc] = acc1[r] + biasv1;
        }
      }
      __syncthreads();
      // cell update: 128 threads x 2 units; c-state in LDS; h stored as coherent dword
      if (tid < 128) {
        const int cb = tid >> 2, up = (tid & 3) * 2;
        const float gi0 = gates[cb * 33 + up],      gi1 = gates[cb * 33 + up + 1];
        const float gj0 = gates[cb * 33 + 8 + up],  gj1 = gates[cb * 33 + 9 + up];
        const float gf0 = gates[cb * 33 + 16 + up], gf1 = gates[cb * 33 + 17 + up];
        const float go0 = gates[cb * 33 + 24 + up], go1 = gates[cb * 33 + 25 + up];
        const float cn0 = cl[cb * 8 + up] * sigm(gf0) + sigm(gi0) * tanhf(gj0);
        const float cn1 = cl[cb * 8 + up + 1] * sigm(gf1) + sigm(gi1) * tanhf(gj1);
        const float hn0 = tanhf(cn0) * sigm(go0);
        const float hn1 = tanhf(cn1) * sigm(go1);
        cl[cb * 8 + up] = cn0;
        cl[cb * 8 + up + 1] = cn1;
        const unsigned int pk = cvt_pk_bf16(hn0, hn1);
        st_cv((unsigned int*)(hmy + ((p + 1) & 1) * 32768 + cb * 1024 + u0 + up), pk);
        if (layer) *(unsigned int*)(hseq + (size_t)t * 32768 + cb * 1024 + u0 + up) = pk;
        if (t == 127) {
          float* ot = out_tail + layer * 32768 + cb * 1024 + u0 + up;
          ot[0] = hn0; ot[1] = hn1;                     // h_last
          ot[65536] = cn0; ot[65537] = cn1;             // c_last
        }
      }
    }
    if (p < 128) gbarF(bar, p + 1, bid);
  }
}

// ---------------- K4: dec_W [1024][32000] f32 -> Wt [32000][1024] bf16 ----------------
__global__ __launch_bounds__(256) void transpose_decw_kernel(
    const float* __restrict__ decW, unsigned short* __restrict__ Wt)
{
  __shared__ float tile[64 * 68];
  const int bid = blockIdx.x;         // 8000 = 16 k-tiles x 500 n-tiles
  const int k0 = (bid & 15) * 64;
  const int n0 = (bid >> 4) * 64;
  const int tid = threadIdx.x;
  {
    const int kl = tid >> 4, c4 = (tid & 15) * 4;
#pragma unroll
    for (int i = 0; i < 4; ++i) {
      const int kr = kl + 16 * i;
      *(float4*)(tile + kr * 68 + c4) =
          *(const float4*)(decW + (size_t)(k0 + kr) * 32000 + n0 + c4);
    }
  }
  __syncthreads();
  {
    const int nl = tid >> 3, kc = (tid & 7) * 8;
#pragma unroll
    for (int h2 = 0; h2 < 2; ++h2) {
      const int n = nl + 32 * h2;
      float tv[8];
#pragma unroll
      for (int q = 0; q < 8; ++q) tv[q] = tile[(kc + q) * 68 + n];
      uint4 u;
      u.x = cvt_pk_bf16(tv[0], tv[1]);
      u.y = cvt_pk_bf16(tv[2], tv[3]);
      u.z = cvt_pk_bf16(tv[4], tv[5]);
      u.w = cvt_pk_bf16(tv[6], tv[7]);
      *(uint4*)(Wt + (size_t)(n0 + n) * 1024 + k0 + kc) = u;
    }
  }
}

// ---------------- K5: decoder bf16 MFMA GEMM, 128x128 tile, BK=32, double-buffered ----------------
__global__ __launch_bounds__(256) void decoder_kernel(
    const unsigned short* __restrict__ A,   // hseq  [4096][1024] bf16
    const unsigned short* __restrict__ Bt,  // Wt    [32000][1024] bf16 (dec_W^T)
    const float* __restrict__ decb,
    float* __restrict__ out)                // [4096][32000] f32
{
  __shared__ unsigned short Al[2][128 * 32];
  __shared__ unsigned short Bl[2][128 * 32];

  const int bid = blockIdx.x;
  const int swz = (bid & 7) * 1000 + (bid >> 3);  // XCD-contiguous tile chunks (8000 % 8 == 0)
  const int mt = swz / 250, nt = swz % 250;
  const int m0 = mt * 128, n0 = nt * 128;

  const int tid = threadIdx.x;
  const int lane = tid & 63;
  const int wv = tid >> 6;
  const int wr = wv >> 1, wc = wv & 1;
  const int l15 = lane & 15, kg = lane >> 4;

  f32x4 acc[4][4];
#pragma unroll
  for (int mi = 0; mi < 4; ++mi)
#pragma unroll
    for (int ni = 0; ni < 4; ++ni) {
      f32x4 z = {0.f, 0.f, 0.f, 0.f};
      acc[mi][ni] = z;
    }

  auto stage = [&](const unsigned short* src, int row0, int k0, unsigned short* lds) {
#pragma unroll
    for (int j = 0; j < 2; ++j) {
      const int chunk = (wv * 2 + j) * 64 + lane;   // 512 x 16B per tile
      const int r = chunk >> 2, kc = chunk & 3;
      const unsigned short* g = src + (size_t)(row0 + r) * 1024 + k0 + kc * 8;
      __builtin_amdgcn_global_load_lds((gas_ptr)g, (las_ptr)(lds + chunk * 8), 16, 0, 0);
    }
  };

  stage(A, m0, 0, Al[0]);
  stage(Bt, n0, 0, Bl[0]);
  __syncthreads();

  int buf = 0;
  for (int kt = 0; kt < 32; ++kt) {
    if (kt < 31) {
      stage(A, m0, (kt + 1) * 32, Al[buf ^ 1]);
      stage(Bt, n0, (kt + 1) * 32, Bl[buf ^ 1]);
    }
    bf16x8 a[4], b[4];
#pragma unroll
    for (int mi = 0; mi < 4; ++mi)
      a[mi] = *(const bf16x8*)&Al[buf][(wr * 64 + mi * 16 + l15) * 32 + kg * 8];
#pragma unroll
    for (int ni = 0; ni < 4; ++ni)
      b[ni] = *(const bf16x8*)&Bl[buf][(wc * 64 + ni * 16 + l15) * 32 + kg * 8];
#pragma unroll
    for (int mi = 0; mi < 4; ++mi)
#pragma unroll
      for (int ni = 0; ni < 4; ++ni)
        acc[mi][ni] = __builtin_amdgcn_mfma_f32_16x16x32_bf16(a[mi], b[ni], acc[mi][ni], 0, 0, 0);
    __syncthreads();  // drains vmcnt (stage kt+1 done) + protects buf reuse
    buf ^= 1;
  }

#pragma unroll
  for (int ni = 0; ni < 4; ++ni) {
    const int ocol = n0 + wc * 64 + ni * 16 + l15;   // C/D: col = lane&15
    const float bv = decb[ocol];
#pragma unroll
    for (int mi = 0; mi < 4; ++mi) {
      const int orow = m0 + wr * 64 + mi * 16 + kg * 4;  // row = (lane>>4)*4 + reg
#pragma unroll
      for (int r = 0; r < 4; ++r)
        out[(size_t)(orow + r) * 32000 + ocol] = acc[mi][ni][r] + bv;
    }
  }
}

extern "C" void kernel_launch(void* const* d_in, const int* in_sizes, int n_in,
                              void* d_out, int out_size, void* d_ws, size_t ws_size,
                              hipStream_t stream) {
  (void)in_sizes; (void)n_in; (void)out_size; (void)ws_size;
  const int* tokens  = (const int*)d_in[0];
  const float* h0_in = (const float*)d_in[1];
  const float* c0_in = (const float*)d_in[2];
  const float* etab  = (const float*)d_in[3];
  const float* lstmW = (const float*)d_in[4];
  const float* lstmb = (const float*)d_in[5];
  const float* decW  = (const float*)d_in[6];
  const float* decb  = (const float*)d_in[7];
  float* out = (float*)d_out;

  char* ws = (char*)d_ws;
  unsigned short* hseq  = (unsigned short*)(ws + 0);         //  8,388,608 B
  char* img             = ws + 8388608;                      // 33,554,432 B (lstm phase)
  unsigned short* Wt    = (unsigned short*)(ws + 8388608);   // 65,536,000 B (decoder phase, overlaps img+xemb)
  unsigned short* xemb  = (unsigned short*)(ws + 41943040);  //  8,388,608 B (lstm phase)
  unsigned short* h0buf = (unsigned short*)(ws + 73924608);  //    131,072 B (bf16, 2 slots)
  unsigned short* h1buf = (unsigned short*)(ws + 74055680);  //    131,072 B
  int* bar              = (int*)(ws + 74186752);             //      3,072 B

  init_kernel<<<128, 256, 0, stream>>>(h0_in, h0buf, h1buf, bar);
  gather_emb<<<4096, 256, 0, stream>>>(tokens, etab, xemb);
  reorg_lstm_w<<<256, 256, 0, stream>>>(lstmW, img);
  lstm_seq_kernel<<<256, 512, 0, stream>>>(img, lstmb, c0_in, xemb,
                                           h0buf, h1buf, hseq,
                                           out + 131072000, bar);
  transpose_decw_kernel<<<8000, 256, 0, stream>>>(decW, Wt);
  decoder_kernel<<<8000, 256, 0, stream>>>(hseq, Wt, decb, out);
}

// Round 7
// 1386.868 us; speedup vs baseline: 28.8381x; 1.9237x over previous
//
#include <hip/hip_runtime.h>

typedef __attribute__((ext_vector_type(8))) short bf16x8;
typedef __attribute__((ext_vector_type(4))) float f32x4;
typedef const __attribute__((address_space(1))) void* gas_ptr;
typedef __attribute__((address_space(3))) void* las_ptr;

__device__ __forceinline__ unsigned short f2bf(float f) {
  unsigned int u = __float_as_uint(f);
  return (unsigned short)((u + 0x7fffu + ((u >> 16) & 1u)) >> 16);  // RNE
}
__device__ __forceinline__ unsigned int cvt_pk_bf16(float a, float b) {
  unsigned int r;
  asm volatile("v_cvt_pk_bf16_f32 %0, %1, %2" : "=v"(r) : "v"(a), "v"(b));
  return r;
}
__device__ __forceinline__ float sigm(float x) { return 1.0f / (1.0f + __expf(-x)); }

// device-coherent (sc0 sc1) store: relaxed agent atomic bypasses L1/L2, lands at IF.
__device__ __forceinline__ void st_cv(unsigned int* p, unsigned int v) {
  __hip_atomic_store(p, v, __ATOMIC_RELAXED, __HIP_MEMORY_SCOPE_AGENT);
}

// ---- fence-free two-level grid barrier (16 leaves x 16 blocks + master) ----
// No __threadfence: h hand-off data uses sc0sc1 accesses (bypass L1/L2), and
// __syncthreads before the signal drains all waves' stores (vmcnt(0) precedes s_barrier).
__device__ __forceinline__ void gbarF(int* bars, int target, int bid) {
  __syncthreads();
  if (threadIdx.x == 0) {
    int* leaf  = bars + (bid & 15) * 32;
    int* mcnt  = bars + 512;
    int* sense = bars + 640;
    if (__hip_atomic_fetch_add(leaf, 1, __ATOMIC_RELAXED, __HIP_MEMORY_SCOPE_AGENT) == 15) {
      __hip_atomic_store(leaf, 0, __ATOMIC_RELAXED, __HIP_MEMORY_SCOPE_AGENT);
      if (__hip_atomic_fetch_add(mcnt, 1, __ATOMIC_RELAXED, __HIP_MEMORY_SCOPE_AGENT) == 15) {
        __hip_atomic_store(mcnt, 0, __ATOMIC_RELAXED, __HIP_MEMORY_SCOPE_AGENT);
        __hip_atomic_store(sense, target, __ATOMIC_RELAXED, __HIP_MEMORY_SCOPE_AGENT);
      }
    }
    while (__hip_atomic_load(sense, __ATOMIC_RELAXED, __HIP_MEMORY_SCOPE_AGENT) < target)
      __builtin_amdgcn_s_sleep(1);
  }
  __syncthreads();
}

// ---------------- K1: h0 -> bf16 double-buffered state, zero barrier ----------------
__global__ __launch_bounds__(256) void init_kernel(
    const float* __restrict__ h0_in,
    unsigned short* __restrict__ h0buf, unsigned short* __restrict__ h1buf,
    int* __restrict__ bar)
{
  const int j = blockIdx.x * 256 + threadIdx.x;   // 0..32767
  if (j < 768) bar[j] = 0;
  h0buf[j] = f2bf(h0_in[j]);                 // layer0 h -> h0buf slot0
  h1buf[32768 + j] = f2bf(h0_in[32768 + j]); // layer1 h -> h1buf slot1
}

// ---------------- K1b: gather emb[tokens] -> xemb bf16 [128*32][1024] ----------------
__global__ __launch_bounds__(256) void gather_emb(
    const int* __restrict__ tokens, const float* __restrict__ etab,
    unsigned short* __restrict__ xemb)
{
  const int r = blockIdx.x;                       // t*32 + b
  const float* src = etab + (size_t)tokens[r] * 1024;
  const int q = threadIdx.x * 4;
  const float4 v = *(const float4*)(src + q);
  uint2 o;
  o.x = cvt_pk_bf16(v.x, v.y);
  o.y = cvt_pk_bf16(v.z, v.w);
  *(uint2*)(xemb + (size_t)r * 1024 + q) = o;
}

// ---------------- K2: lstm_W -> per-block MFMA-fragment-slot images (bf16) ----------------
// Image for lstm block bid (layer=bid>>7, u0=(bid&127)*8): 8192 slots x 16B, slot
// S = kt*128 + tn*64 + lane ; content = W[kt*32 + (lane>>4)*8 .. +8][gcol] as 8 bf16,
// where c = tn*16 + (lane&15), gcol = (c>>3)*1024 + u0 + (c&7).
__global__ __launch_bounds__(256) void reorg_lstm_w(
    const float* __restrict__ W, char* __restrict__ wimg)
{
  __shared__ float tile[64 * 36];
  const int bid = blockIdx.x;            // 256 = lstm block id
  const int layer = bid >> 7;
  const int u0 = (bid & 127) * 8;
  const int tid = threadIdx.x;
  const float* Wl = W + (size_t)layer * 2048 * 4096;
  char* img = wimg + (size_t)bid * 131072;
  const int kl = tid >> 2, g = tid & 3;                                  // load map
  const int row = tid & 15, ksub = (tid >> 4) & 3;                       // emit map
  const int tn = (tid >> 6) & 1, kl2 = tid >> 7;
  const int c = tn * 16 + row;
#pragma unroll 1
  for (int kt = 0; kt < 32; ++kt) {
    const float* src = Wl + (size_t)(kt * 64 + kl) * 4096 + g * 1024 + u0;
    const float4 v0 = *(const float4*)src;
    const float4 v1 = *(const float4*)(src + 4);
    *(float4*)(tile + kl * 36 + g * 8) = v0;
    *(float4*)(tile + kl * 36 + g * 8 + 4) = v1;
    __syncthreads();
    const int kbase = kl2 * 32 + ksub * 8;
    uint4 u;
    u.x = cvt_pk_bf16(tile[(kbase + 0) * 36 + c], tile[(kbase + 1) * 36 + c]);
    u.y = cvt_pk_bf16(tile[(kbase + 2) * 36 + c], tile[(kbase + 3) * 36 + c]);
    u.z = cvt_pk_bf16(tile[(kbase + 4) * 36 + c], tile[(kbase + 5) * 36 + c]);
    u.w = cvt_pk_bf16(tile[(kbase + 6) * 36 + c], tile[(kbase + 7) * 36 + c]);
    const int S = (kt * 2 + kl2) * 128 + tn * 64 + ksub * 16 + row;
    *(uint4*)(img + (size_t)S * 16) = u;
    __syncthreads();
  }
}

// ---------------- K3: pipelined 2-layer LSTM scan; 16B coherent x-loads ----------------
// 256 blocks x 512 threads, 1/CU. Block: layer=bid>>7, 32 gate-cols at u0=(bid&127)*8.
// Wave w: tb=w&1 (16 batch rows), kq=w>>1 (512-K quarter). Each wave: 16 A-frags (read once
// as global_load_dwordx4 sc0 sc1 -> full 64B line per instr), 32 MFMAs (both tn share A).
__global__ __launch_bounds__(512, 1) void lstm_seq_kernel(
    const char* __restrict__ wimg, const float* __restrict__ bias,
    const float* __restrict__ c0_in,
    const unsigned short* __restrict__ xemb,
    unsigned short* __restrict__ h0buf, unsigned short* __restrict__ h1buf,
    unsigned short* __restrict__ hseq,
    float* __restrict__ out_tail, int* __restrict__ bar)
{
  __shared__ __align__(16) char smem[148608];
  char* wlds   = smem;                        // 131072: W fragment slots
  float* red   = (float*)(smem + 131072);     //  12288: K-quarter partials (12 x 64 x f32x4)
  float* gates = (float*)(smem + 143360);     //   4224: [32 b][33] padded
  float* cl    = (float*)(smem + 147584);     //   1024: c-state [32 b][8 u]

  const int tid = threadIdx.x;
  const int bid = blockIdx.x;
  const int layer = bid >> 7;
  const int u0 = (bid & 127) * 8;
  const int lane = tid & 63, w = tid >> 6;
  const int tb = w & 1, kq = w >> 1;
  const int row = tb * 16 + (lane & 15);
  const int kg = lane >> 4;
  unsigned short* hmy = layer ? h1buf : h0buf;

  // one-time: W image -> LDS (linear 16B, coalesced), c-state -> LDS
  {
    const char* img = wimg + (size_t)bid * 131072;
#pragma unroll 1
    for (int i = 0; i < 16; ++i) {
      const int off = (i * 512 + tid) * 16;
      __builtin_amdgcn_global_load_lds((gas_ptr)(img + off), (las_ptr)(wlds + off), 16, 0, 0);
    }
    if (tid < 256) cl[tid] = c0_in[layer * 32768 + (tid >> 3) * 1024 + u0 + (tid & 7)];
  }
  const int cc = lane & 15;
  const float biasv0 = bias[layer * 4096 + (cc >> 3) * 1024 + u0 + (cc & 7)];         // tn=0 col
  const float biasv1 = bias[layer * 4096 + ((cc + 16) >> 3) * 1024 + u0 + (cc & 7)];  // tn=1 col
  asm volatile("s_waitcnt vmcnt(0)");
  __syncthreads();

  const char* wq = wlds + (size_t)(kq * 16 * 128 + lane) * 16;

  for (int p = 0; p <= 128; ++p) {
    const bool active = layer ? (p >= 1) : (p < 128);
    if (active) {
      const int t = layer ? (p - 1) : p;
      // this wave's x source: kq<2 -> low-K input (emb for L0 cached, h0 cur for L1 coherent);
      // kq>=2 -> own h(prev), coherent. Byte base for frag j: xb + j*64.
      const char* xb;
      bool coh;
      if (kq < 2) {
        if (layer == 0) {
          xb = (const char*)xemb + (size_t)t * 65536 + row * 2048 + (kq & 1) * 1024 + kg * 16;
          coh = false;
        } else {
          xb = (const char*)h0buf + (p & 1) * 65536 + row * 2048 + (kq & 1) * 1024 + kg * 16;
          coh = true;
        }
      } else {
        xb = (const char*)hmy + (p & 1) * 65536 + row * 2048 + (kq & 1) * 1024 + kg * 16;
        coh = true;
      }

      bf16x8 a[16];
      if (!coh) {
#pragma unroll
        for (int j = 0; j < 16; ++j) a[j] = *(const bf16x8*)(xb + j * 64);
      } else {
        // 16B device-coherent loads: one instr per frag, full 64B line per instr
#pragma unroll
        for (int j = 0; j < 16; ++j)
          asm volatile("global_load_dwordx4 %0, %1, off sc0 sc1"
                       : "=v"(a[j]) : "v"(xb + j * 64) : "memory");
        asm volatile("s_waitcnt vmcnt(0)" ::: "memory");
        __builtin_amdgcn_sched_barrier(0);  // rule #18: don't hoist MFMA past the waitcnt
      }

      f32x4 acc0 = {0.f, 0.f, 0.f, 0.f}, acc1 = {0.f, 0.f, 0.f, 0.f};
#pragma unroll
      for (int j = 0; j < 16; ++j) {
        const bf16x8 b0 = *(const bf16x8*)(wq + (size_t)j * 2048);
        const bf16x8 b1 = *(const bf16x8*)(wq + (size_t)j * 2048 + 1024);
        acc0 = __builtin_amdgcn_mfma_f32_16x16x32_bf16(a[j], b0, acc0, 0, 0, 0);
        acc1 = __builtin_amdgcn_mfma_f32_16x16x32_bf16(a[j], b1, acc1, 0, 0, 0);
      }

      // 4-way K-quarter reduction: kq>0 waves dump, kq==0 waves sum + bias -> gates
      if (kq > 0) {
        const int s0 = (((kq - 1) * 2 + tb) * 2 + 0) * 64 + lane;
        const int s1 = (((kq - 1) * 2 + tb) * 2 + 1) * 64 + lane;
        *(f32x4*)(red + s0 * 4) = acc0;
        *(f32x4*)(red + s1 * 4) = acc1;
      }
      __syncthreads();
      if (kq == 0) {
#pragma unroll
        for (int q = 1; q < 4; ++q) {
          const f32x4 o0 = *(const f32x4*)(red + ((((q - 1) * 2 + tb) * 2 + 0) * 64 + lane) * 4);
          const f32x4 o1 = *(const f32x4*)(red + ((((q - 1) * 2 + tb) * 2 + 1) * 64 + lane) * 4);
#pragma unroll
          for (int r = 0; r < 4; ++r) { acc0[r] += o0[r]; acc1[r] += o1[r]; }
        }
        const int rb = tb * 16 + kg * 4;
#pragma unroll
        for (int r = 0; r < 4; ++r) {
          gates[(rb + r) * 33 + cc] = acc0[r] + biasv0;
          gates[(rb + r) * 33 + 16 + cc] = acc1[r] + biasv1;
        }
      }
      __syncthreads();
      // cell update: 128 threads x 2 units; c-state in LDS; h stored as coherent dword
      if (tid < 128) {
        const int cb = tid >> 2, up = (tid & 3) * 2;
        const float gi0 = gates[cb * 33 + up],      gi1 = gates[cb * 33 + up + 1];
        const float gj0 = gates[cb * 33 + 8 + up],  gj1 = gates[cb * 33 + 9 + up];
        const float gf0 = gates[cb * 33 + 16 + up], gf1 = gates[cb * 33 + 17 + up];
        const float go0 = gates[cb * 33 + 24 + up], go1 = gates[cb * 33 + 25 + up];
        const float cn0 = cl[cb * 8 + up] * sigm(gf0) + sigm(gi0) * tanhf(gj0);
        const float cn1 = cl[cb * 8 + up + 1] * sigm(gf1) + sigm(gi1) * tanhf(gj1);
        const float hn0 = tanhf(cn0) * sigm(go0);
        const float hn1 = tanhf(cn1) * sigm(go1);
        cl[cb * 8 + up] = cn0;
        cl[cb * 8 + up + 1] = cn1;
        const unsigned int pk = cvt_pk_bf16(hn0, hn1);
        st_cv((unsigned int*)(hmy + ((p + 1) & 1) * 32768 + cb * 1024 + u0 + up), pk);
        if (layer) *(unsigned int*)(hseq + (size_t)t * 32768 + cb * 1024 + u0 + up) = pk;
        if (t == 127) {
          float* ot = out_tail + layer * 32768 + cb * 1024 + u0 + up;
          ot[0] = hn0; ot[1] = hn1;                     // h_last
          ot[65536] = cn0; ot[65537] = cn1;             // c_last
        }
      }
    }
    if (p < 128) gbarF(bar, p + 1, bid);
  }
}

// ---------------- K4: dec_W [1024][32000] f32 -> Wt [32000][1024] bf16 ----------------
__global__ __launch_bounds__(256) void transpose_decw_kernel(
    const float* __restrict__ decW, unsigned short* __restrict__ Wt)
{
  __shared__ float tile[64 * 68];
  const int bid = blockIdx.x;         // 8000 = 16 k-tiles x 500 n-tiles
  const int k0 = (bid & 15) * 64;
  const int n0 = (bid >> 4) * 64;
  const int tid = threadIdx.x;
  {
    const int kl = tid >> 4, c4 = (tid & 15) * 4;
#pragma unroll
    for (int i = 0; i < 4; ++i) {
      const int kr = kl + 16 * i;
      *(float4*)(tile + kr * 68 + c4) =
          *(const float4*)(decW + (size_t)(k0 + kr) * 32000 + n0 + c4);
    }
  }
  __syncthreads();
  {
    const int nl = tid >> 3, kc = (tid & 7) * 8;
#pragma unroll
    for (int h2 = 0; h2 < 2; ++h2) {
      const int n = nl + 32 * h2;
      float tv[8];
#pragma unroll
      for (int q = 0; q < 8; ++q) tv[q] = tile[(kc + q) * 68 + n];
      uint4 u;
      u.x = cvt_pk_bf16(tv[0], tv[1]);
      u.y = cvt_pk_bf16(tv[2], tv[3]);
      u.z = cvt_pk_bf16(tv[4], tv[5]);
      u.w = cvt_pk_bf16(tv[6], tv[7]);
      *(uint4*)(Wt + (size_t)(n0 + n) * 1024 + k0 + kc) = u;
    }
  }
}

// ---------------- K5: decoder bf16 MFMA GEMM, 128x128 tile, BK=32, double-buffered ----------------
__global__ __launch_bounds__(256) void decoder_kernel(
    const unsigned short* __restrict__ A,   // hseq  [4096][1024] bf16
    const unsigned short* __restrict__ Bt,  // Wt    [32000][1024] bf16 (dec_W^T)
    const float* __restrict__ decb,
    float* __restrict__ out)                // [4096][32000] f32
{
  __shared__ unsigned short Al[2][128 * 32];
  __shared__ unsigned short Bl[2][128 * 32];

  const int bid = blockIdx.x;
  const int swz = (bid & 7) * 1000 + (bid >> 3);  // XCD-contiguous tile chunks (8000 % 8 == 0)
  const int mt = swz / 250, nt = swz % 250;
  const int m0 = mt * 128, n0 = nt * 128;

  const int tid = threadIdx.x;
  const int lane = tid & 63;
  const int wv = tid >> 6;
  const int wr = wv >> 1, wc = wv & 1;
  const int l15 = lane & 15, kg = lane >> 4;

  f32x4 acc[4][4];
#pragma unroll
  for (int mi = 0; mi < 4; ++mi)
#pragma unroll
    for (int ni = 0; ni < 4; ++ni) {
      f32x4 z = {0.f, 0.f, 0.f, 0.f};
      acc[mi][ni] = z;
    }

  auto stage = [&](const unsigned short* src, int row0, int k0, unsigned short* lds) {
#pragma unroll
    for (int j = 0; j < 2; ++j) {
      const int chunk = (wv * 2 + j) * 64 + lane;   // 512 x 16B per tile
      const int r = chunk >> 2, kc = chunk & 3;
      const unsigned short* g = src + (size_t)(row0 + r) * 1024 + k0 + kc * 8;
      __builtin_amdgcn_global_load_lds((gas_ptr)g, (las_ptr)(lds + chunk * 8), 16, 0, 0);
    }
  };

  stage(A, m0, 0, Al[0]);
  stage(Bt, n0, 0, Bl[0]);
  __syncthreads();

  int buf = 0;
  for (int kt = 0; kt < 32; ++kt) {
    if (kt < 31) {
      stage(A, m0, (kt + 1) * 32, Al[buf ^ 1]);
      stage(Bt, n0, (kt + 1) * 32, Bl[buf ^ 1]);
    }
    bf16x8 a[4], b[4];
#pragma unroll
    for (int mi = 0; mi < 4; ++mi)
      a[mi] = *(const bf16x8*)&Al[buf][(wr * 64 + mi * 16 + l15) * 32 + kg * 8];
#pragma unroll
    for (int ni = 0; ni < 4; ++ni)
      b[ni] = *(const bf16x8*)&Bl[buf][(wc * 64 + ni * 16 + l15) * 32 + kg * 8];
#pragma unroll
    for (int mi = 0; mi < 4; ++mi)
#pragma unroll
      for (int ni = 0; ni < 4; ++ni)
        acc[mi][ni] = __builtin_amdgcn_mfma_f32_16x16x32_bf16(a[mi], b[ni], acc[mi][ni], 0, 0, 0);
    __syncthreads();  // drains vmcnt (stage kt+1 done) + protects buf reuse
    buf ^= 1;
  }

#pragma unroll
  for (int ni = 0; ni < 4; ++ni) {
    const int ocol = n0 + wc * 64 + ni * 16 + l15;   // C/D: col = lane&15
    const float bv = decb[ocol];
#pragma unroll
    for (int mi = 0; mi < 4; ++mi) {
      const int orow = m0 + wr * 64 + mi * 16 + kg * 4;  // row = (lane>>4)*4 + reg
#pragma unroll
      for (int r = 0; r < 4; ++r)
        out[(size_t)(orow + r) * 32000 + ocol] = acc[mi][ni][r] + bv;
    }
  }
}

extern "C" void kernel_launch(void* const* d_in, const int* in_sizes, int n_in,
                              void* d_out, int out_size, void* d_ws, size_t ws_size,
                              hipStream_t stream) {
  (void)in_sizes; (void)n_in; (void)out_size; (void)ws_size;
  const int* tokens  = (const int*)d_in[0];
  const float* h0_in = (const float*)d_in[1];
  const float* c0_in = (const float*)d_in[2];
  const float* etab  = (const float*)d_in[3];
  const float* lstmW = (const float*)d_in[4];
  const float* lstmb = (const float*)d_in[5];
  const float* decW  = (const float*)d_in[6];
  const float* decb  = (const float*)d_in[7];
  float* out = (float*)d_out;

  char* ws = (char*)d_ws;
  unsigned short* hseq  = (unsigned short*)(ws + 0);         //  8,388,608 B
  char* img             = ws + 8388608;                      // 33,554,432 B (lstm phase)
  unsigned short* Wt    = (unsigned short*)(ws + 8388608);   // 65,536,000 B (decoder phase, overlaps img+xemb)
  unsigned short* xemb  = (unsigned short*)(ws + 41943040);  //  8,388,608 B (lstm phase)
  unsigned short* h0buf = (unsigned short*)(ws + 73924608);  //    131,072 B (bf16, 2 slots)
  unsigned short* h1buf = (unsigned short*)(ws + 74055680);  //    131,072 B
  int* bar              = (int*)(ws + 74186752);             //      3,072 B

  init_kernel<<<128, 256, 0, stream>>>(h0_in, h0buf, h1buf, bar);
  gather_emb<<<4096, 256, 0, stream>>>(tokens, etab, xemb);
  reorg_lstm_w<<<256, 256, 0, stream>>>(lstmW, img);
  lstm_seq_kernel<<<256, 512, 0, stream>>>(img, lstmb, c0_in, xemb,
                                           h0buf, h1buf, hseq,
                                           out + 131072000, bar);
  transpose_decw_kernel<<<8000, 256, 0, stream>>>(decW, Wt);
  decoder_kernel<<<8000, 256, 0, stream>>>(hseq, Wt, decb, out);
}